// Round 3
// baseline (615.824 us; speedup 1.0000x reference)
//
#include <hip/hip_runtime.h>
#include <hip/hip_fp16.h>

#define BN_EPS 1e-5f
#define BK 512        // dst-nodes per bucket (contiguous node range)
#define NBMAX 128
#define ECH 8192      // edges per scatter block
#define BCAP 9216     // fixed per-bucket capacity (mean 8163, sigma~90 -> 11+ sigma)

typedef _Float16 half_t;
typedef _Float16 half8 __attribute__((ext_vector_type(8)));
typedef float floatx4 __attribute__((ext_vector_type(4)));

__device__ __forceinline__ int xcc_id() {
  int x;
  asm volatile("s_getreg_b32 %0, hwreg(HW_REG_XCC_ID)" : "=s"(x));
  return x;
}

// ---------------------------------------------------------------------------
// Preprocess, fixed-stride buckets: bucket b owns tmp/esrc[b*BCAP ..). No
// global histogram or scan passes; per-bucket cursors reserve runs directly.
// CSR is strided (gaps between buckets) -> aggs use explicit offs/offe.
// ---------------------------------------------------------------------------

// blocks [0, sb): scatter {src,dst} into bucket-major tmp (~670B runs/bucket).
// blocks [sb, ..): fp32 -> fp16 copy of x (independent work, merged dispatch).
__global__ __launch_bounds__(256) void scatter_cvt_kernel(
    const int* __restrict__ src, const int* __restrict__ dst,
    int* __restrict__ bcursor, int2* __restrict__ tmp,
    const float* __restrict__ x, __half* __restrict__ x16,
    int E, int nb, int sb, int n4) {
  const int t = threadIdx.x;
  if (blockIdx.x >= sb) {
    int i = (blockIdx.x - sb) * 256 + t;
    if (i < n4) {
      float4 v = *(const float4*)(x + (size_t)i * 4);
      union { __half h[4]; float2 f; } u;
      u.h[0] = __float2half_rn(v.x);
      u.h[1] = __float2half_rn(v.y);
      u.h[2] = __float2half_rn(v.z);
      u.h[3] = __float2half_rn(v.w);
      *(float2*)(x16 + (size_t)i * 4) = u.f;
    }
    return;
  }
  __shared__ int h[NBMAX];
  for (int i = t; i < nb; i += 256) h[i] = 0;
  __syncthreads();
  const int base = blockIdx.x * ECH;
#pragma unroll 8
  for (int p = 0; p < ECH / 256; ++p) {
    int e = base + p * 256 + t;
    if (e < E) atomicAdd(&h[dst[e] >> 9], 1);
  }
  __syncthreads();
  for (int i = t; i < nb; i += 256) {
    int c = h[i];
    h[i] = c ? (i * BCAP + atomicAdd(&bcursor[i], c)) : 0;  // contiguous run
  }
  __syncthreads();
#pragma unroll 8
  for (int p = 0; p < ECH / 256; ++p) {
    int e = base + p * 256 + t;
    if (e < E) {
      int s = src[e], d = dst[e];
      int pos = atomicAdd(&h[d >> 9], 1);
      tmp[pos] = make_int2(s, d);
    }
  }
}

// One block per bucket: LDS degree count -> local scan -> offs/offe/dinv/esrc.
// Also pre-scales this bucket's x16 rows by dinv[row] (dinv-fold for layer 0:
// agg64 then computes out = di * (sum_e x16'[src_e] + x16'[gi]) with no
// per-edge dinv lookup).
__global__ __launch_bounds__(256) void bucket_finalize_kernel(
    const int2* __restrict__ tmp, const int* __restrict__ bcursor,
    int* __restrict__ offs, int* __restrict__ offe, float* __restrict__ dinv,
    int* __restrict__ esrc, __half* __restrict__ x16, int n) {
  __shared__ int deg[BK];
  __shared__ int cur[BK];
  __shared__ float fdi[BK];
  __shared__ int ts[256];
  const int t = threadIdx.x;
  const int b = blockIdx.x;
  const int nbase = b * BK;
  const int nn = min(BK, n - nbase);
  const int cnt = bcursor[b];
  const int2* tp = tmp + (size_t)b * BCAP;
  for (int i = t; i < nn; i += 256) deg[i] = 0;
  __syncthreads();
  for (int e = t; e < cnt; e += 256)
    atomicAdd(&deg[tp[e].y - nbase], 1);
  __syncthreads();
  // exclusive scan of 512 degrees (thread t handles 2t, 2t+1)
  int d0 = (2 * t < nn) ? deg[2 * t] : 0;
  int d1 = (2 * t + 1 < nn) ? deg[2 * t + 1] : 0;
  ts[t] = d0 + d1;
  __syncthreads();
  for (int o = 1; o < 256; o <<= 1) {
    int v = (t >= o) ? ts[t - o] : 0;
    __syncthreads();
    ts[t] += v;
    __syncthreads();
  }
  int base = b * BCAP + ((t == 0) ? 0 : ts[t - 1]);
  if (2 * t < nn) {
    float di = rsqrtf(1.0f + (float)d0);
    offs[nbase + 2 * t] = base;
    offe[nbase + 2 * t] = base + d0;
    cur[2 * t] = base;
    fdi[2 * t] = di;
    dinv[nbase + 2 * t] = di;
  }
  if (2 * t + 1 < nn) {
    float di = rsqrtf(1.0f + (float)d1);
    offs[nbase + 2 * t + 1] = base + d0;
    offe[nbase + 2 * t + 1] = base + d0 + d1;
    cur[2 * t + 1] = base + d0;
    fdi[2 * t + 1] = di;
    dinv[nbase + 2 * t + 1] = di;
  }
  __syncthreads();
  for (int e = t; e < cnt; e += 256) {
    int2 r = tp[e];
    int pos = atomicAdd(&cur[r.y - nbase], 1);
    esrc[pos] = r.x;
  }
  // pre-scale x16 rows of this bucket by dinv[row] (32 half2 per row)
  __half2* xp = (__half2*)x16;
  for (int i = t; i < nn * 32; i += 256) {
    int nl = i >> 5;
    size_t idx = (((size_t)(nbase + nl)) << 5) + (i & 31);
    float2 v = __half22float2(xp[idx]);
    float s = fdi[nl];
    xp[idx] = __floats2half2_rn(v.x * s, v.y * s);
  }
}

// ---------------------------------------------------------------------------
// MFMA fp16 GEMM (fp32 accumulate).  256 thr = 4 waves; 128-row tile.
// Frag layouts (m89/m120): A[m=lane&15][k=quad*8+j]; B[k][n=lane&15];
// C/D row=quad*4+reg, col=lane&15.  LDS stride 72 halfs (2-way = free).
// EPI: 0 none, 1 bias+relu, 2 bias, 3 bias+BN+relu,
//      4 row-scale (bias ptr = per-row dinv; writes dinv[row]*acc).
// ---------------------------------------------------------------------------

template <int FIN, int FOUT, int EPI, bool HALFOUT>
__global__ __launch_bounds__(256) void mgemm_kernel(
    const __half* __restrict__ X, const float* __restrict__ W,
    const float* __restrict__ bias, const float* __restrict__ gam,
    const float* __restrict__ bet, const float* __restrict__ mean,
    const float* __restrict__ var, void* __restrict__ Yv, int n) {
  constexpr int LDK = 72;
  constexpr int NCI = FOUT / 16;
  __shared__ half_t Asm[128 * LDK];
  __shared__ half_t Bsm[FOUT * LDK];

  const int t = threadIdx.x;
  const int wave = t >> 6, lane = t & 63;
  const int quad = lane >> 4, l16 = lane & 15;
  const int rowBase = blockIdx.x * 128;

  floatx4 acc[2][NCI];
#pragma unroll
  for (int i = 0; i < 2; ++i)
#pragma unroll
    for (int ci = 0; ci < NCI; ++ci) acc[i][ci] = (floatx4){0.f, 0.f, 0.f, 0.f};

  for (int kc = 0; kc < FIN; kc += 64) {
    __syncthreads();
    {
      const int kq = t & 15, m0 = t >> 4;
#pragma unroll
      for (int p = 0; p < 8; ++p) {
        int m = p * 16 + m0;
        int row = rowBase + m;
        uint2 v = make_uint2(0u, 0u);
        if (row < n) v = *(const uint2*)(X + (size_t)row * FIN + kc + kq * 4);
        *(uint2*)&Asm[m * LDK + kq * 4] = v;
      }
    }
    {
#pragma unroll
      for (int c0 = 0; c0 < FOUT * 16; c0 += 256) {
        int c = c0 + t;
        int nn = c % FOUT;
        int kg = (c / FOUT) * 4;
        const float* wp = W + (size_t)(kc + kg) * FOUT + nn;
        half_t* d = &Bsm[nn * LDK + kg];
        d[0] = (half_t)wp[0];
        d[1] = (half_t)wp[FOUT];
        d[2] = (half_t)wp[2 * FOUT];
        d[3] = (half_t)wp[3 * FOUT];
      }
    }
    __syncthreads();
#pragma unroll
    for (int kk = 0; kk < 2; ++kk) {
      half8 a0 = *(const half8*)&Asm[(wave * 32 + l16) * LDK + kk * 32 + quad * 8];
      half8 a1 = *(const half8*)&Asm[(wave * 32 + 16 + l16) * LDK + kk * 32 + quad * 8];
#pragma unroll
      for (int ci = 0; ci < NCI; ++ci) {
        half8 b = *(const half8*)&Bsm[(ci * 16 + l16) * LDK + kk * 32 + quad * 8];
        acc[0][ci] = __builtin_amdgcn_mfma_f32_16x16x32_f16(a0, b, acc[0][ci], 0, 0, 0);
        acc[1][ci] = __builtin_amdgcn_mfma_f32_16x16x32_f16(a1, b, acc[1][ci], 0, 0, 0);
      }
    }
  }

  float sc[NCI], sh[NCI];
#pragma unroll
  for (int ci = 0; ci < NCI; ++ci) {
    int col = ci * 16 + l16;
    if constexpr (EPI == 3) {
      float s = gam[col] * rsqrtf(var[col] + BN_EPS);
      sc[ci] = s;
      sh[ci] = (bias[col] - mean[col]) * s + bet[col];
    } else if constexpr (EPI == 1 || EPI == 2) {
      sc[ci] = 1.f;
      sh[ci] = bias[col];
    } else {
      sc[ci] = 1.f;
      sh[ci] = 0.f;
    }
  }
  float rs[2][4];
  if constexpr (EPI == 4) {
#pragma unroll
    for (int ri = 0; ri < 2; ++ri)
#pragma unroll
      for (int r = 0; r < 4; ++r) {
        int row = rowBase + wave * 32 + ri * 16 + quad * 4 + r;
        rs[ri][r] = (row < n) ? bias[row] : 0.f;   // bias ptr = dinv (per-row)
      }
  }
#pragma unroll
  for (int ri = 0; ri < 2; ++ri)
#pragma unroll
    for (int ci = 0; ci < NCI; ++ci) {
      int col = ci * 16 + l16;
#pragma unroll
      for (int r = 0; r < 4; ++r) {
        int row = rowBase + wave * 32 + ri * 16 + quad * 4 + r;
        if (row < n) {
          float v = acc[ri][ci][r];
          if constexpr (EPI == 4) v *= rs[ri][r];
          if constexpr (EPI == 1 || EPI == 2 || EPI == 3) v = fmaf(v, sc[ci], sh[ci]);
          if constexpr (EPI == 1 || EPI == 3) v = fmaxf(v, 0.f);
          if constexpr (HALFOUT)
            ((half_t*)Yv)[(size_t)row * FOUT + col] = (half_t)v;
          else
            ((float*)Yv)[(size_t)row * FOUT + col] = v;
        }
      }
    }
}

// ---------------------------------------------------------------------------
// Fused MLP: Y = relu(X@W1+b1)@W2 + b2.  H kept in LDS (fp16, stride 136).
// ---------------------------------------------------------------------------

__global__ __launch_bounds__(256) void mlp_kernel(
    const __half* __restrict__ X, const float* __restrict__ W1,
    const float* __restrict__ b1f, const float* __restrict__ W2,
    const float* __restrict__ b2f, float* __restrict__ Y, int n) {
  constexpr int LDK = 72;
  constexpr int LDK2 = 136;
  __shared__ half_t smem[(128 + 64) * LDK2];
  half_t* As1 = smem;
  half_t* Bs1 = smem + 128 * LDK;
  half_t* As2 = smem;
  half_t* Bs2 = smem + 128 * LDK2;

  const int t = threadIdx.x;
  const int wave = t >> 6, lane = t & 63;
  const int quad = lane >> 4, l16 = lane & 15;
  const int rowBase = blockIdx.x * 128;

  floatx4 acc[2][8];
#pragma unroll
  for (int i = 0; i < 2; ++i)
#pragma unroll
    for (int ci = 0; ci < 8; ++ci) acc[i][ci] = (floatx4){0.f, 0.f, 0.f, 0.f};

  for (int kc = 0; kc < 128; kc += 64) {
    __syncthreads();
    {
      const int kq = t & 15, m0 = t >> 4;
#pragma unroll
      for (int p = 0; p < 8; ++p) {
        int m = p * 16 + m0;
        int row = rowBase + m;
        uint2 v = make_uint2(0u, 0u);
        if (row < n) v = *(const uint2*)(X + (size_t)row * 128 + kc + kq * 4);
        *(uint2*)&As1[m * LDK + kq * 4] = v;
      }
    }
    {
#pragma unroll
      for (int c0 = 0; c0 < 128 * 16; c0 += 256) {
        int c = c0 + t;
        int nn = c & 127;
        int kg = (c >> 7) << 2;
        const float* wp = W1 + (size_t)(kc + kg) * 128 + nn;
        half_t* d = &Bs1[nn * LDK + kg];
        d[0] = (half_t)wp[0];
        d[1] = (half_t)wp[128];
        d[2] = (half_t)wp[256];
        d[3] = (half_t)wp[384];
      }
    }
    __syncthreads();
#pragma unroll
    for (int kk = 0; kk < 2; ++kk) {
      half8 a0 = *(const half8*)&As1[(wave * 32 + l16) * LDK + kk * 32 + quad * 8];
      half8 a1 = *(const half8*)&As1[(wave * 32 + 16 + l16) * LDK + kk * 32 + quad * 8];
#pragma unroll
      for (int ci = 0; ci < 8; ++ci) {
        half8 b = *(const half8*)&Bs1[(ci * 16 + l16) * LDK + kk * 32 + quad * 8];
        acc[0][ci] = __builtin_amdgcn_mfma_f32_16x16x32_f16(a0, b, acc[0][ci], 0, 0, 0);
        acc[1][ci] = __builtin_amdgcn_mfma_f32_16x16x32_f16(a1, b, acc[1][ci], 0, 0, 0);
      }
    }
  }
  __syncthreads();

#pragma unroll
  for (int ri = 0; ri < 2; ++ri)
#pragma unroll
    for (int ci = 0; ci < 8; ++ci) {
      int col = ci * 16 + l16;
      float bz = b1f[col];
#pragma unroll
      for (int r = 0; r < 4; ++r) {
        int m = wave * 32 + ri * 16 + quad * 4 + r;
        As2[m * LDK2 + col] = (half_t)fmaxf(acc[ri][ci][r] + bz, 0.f);
      }
    }
  {
#pragma unroll
    for (int c0 = 0; c0 < 64 * 32; c0 += 256) {
      int c = c0 + t;
      int nn = c & 63;
      int kg = (c >> 6) << 2;
      const float* wp = W2 + (size_t)kg * 64 + nn;
      half_t* d = &Bs2[nn * LDK2 + kg];
      d[0] = (half_t)wp[0];
      d[1] = (half_t)wp[64];
      d[2] = (half_t)wp[128];
      d[3] = (half_t)wp[192];
    }
  }
  __syncthreads();

  floatx4 acc2[2][4];
#pragma unroll
  for (int i = 0; i < 2; ++i)
#pragma unroll
    for (int ci = 0; ci < 4; ++ci) acc2[i][ci] = (floatx4){0.f, 0.f, 0.f, 0.f};
#pragma unroll
  for (int kk = 0; kk < 4; ++kk) {
    half8 a0 = *(const half8*)&As2[(wave * 32 + l16) * LDK2 + kk * 32 + quad * 8];
    half8 a1 = *(const half8*)&As2[(wave * 32 + 16 + l16) * LDK2 + kk * 32 + quad * 8];
#pragma unroll
    for (int ci = 0; ci < 4; ++ci) {
      half8 b = *(const half8*)&Bs2[(ci * 16 + l16) * LDK2 + kk * 32 + quad * 8];
      acc2[0][ci] = __builtin_amdgcn_mfma_f32_16x16x32_f16(a0, b, acc2[0][ci], 0, 0, 0);
      acc2[1][ci] = __builtin_amdgcn_mfma_f32_16x16x32_f16(a1, b, acc2[1][ci], 0, 0, 0);
    }
  }
#pragma unroll
  for (int ri = 0; ri < 2; ++ri)
#pragma unroll
    for (int ci = 0; ci < 4; ++ci) {
      int col = ci * 16 + l16;
      float bz = b2f[col];
#pragma unroll
      for (int r = 0; r < 4; ++r) {
        int row = rowBase + wave * 32 + ri * 16 + quad * 4 + r;
        if (row < n) Y[(size_t)row * 64 + col] = acc2[ri][ci][r] + bz;
      }
    }
}

// ---------------------------------------------------------------------------
// XCC-self-aware sliced aggregations.  Each block reads its actual XCD id
// from HW_REG_XCC_ID and processes ONLY the feature slice owned by that XCD
// (slice = 32 feats = 64B; table slice = N*64B = 3.2MB < 4MB per-XCD L2).
// Disjoint node chunks come from a per-slice global cursor (work stealing),
// so slice->XCD locality holds regardless of the HW block->XCD mapping
// (round-1 falsified the blockIdx%8 assumption: FETCH stayed 8x table size).
// One wave per node; lane groups g=0..3 handle edges e+g with a 4-deep
// unroll (16 edges in flight, matching mean degree 16); shfl reduce; group 0
// adds the (pre-scaled) self row and stores 64B.  Pure sums: all dinv
// factors folded upstream (finalize for x16, GEMM EPI=4 for t1).
// ---------------------------------------------------------------------------

#define CHN 32   // nodes per cursor grab (8 per wave)

__global__ __launch_bounds__(256) void agg64_xcc_kernel(
    const __half* __restrict__ h, const int* __restrict__ offs,
    const int* __restrict__ offe, const int* __restrict__ esrc,
    const float* __restrict__ dinv, __half* __restrict__ out,
    int* __restrict__ cursor, int n) {
  const int slice = xcc_id() & 1;           // 3.2MB slice, 4 XCDs per slice
  int* cur = cursor + slice;
  const int t = threadIdx.x;
  const int wave = t >> 6, lane = t & 63;
  const int grp = lane >> 4;
  const int fo = slice * 16 + (lane & 15);  // half2 idx within 32-half2 row
  const __half2* hp = (const __half2*)h;
  __shared__ int sb;

  for (;;) {
    if (t == 0) sb = atomicAdd(cur, 1);
    __syncthreads();
    const int nbase = sb * CHN;
    __syncthreads();
    if (nbase >= n) return;
    const int g0 = nbase + wave * (CHN / 4);
#pragma unroll 1
    for (int w = 0; w < CHN / 4; ++w) {
      const int gi = g0 + w;
      if (gi >= n) break;
      const float di = dinv[gi];
      int e = offs[gi] + grp;
      const int e1 = offe[gi];
      float ax = 0.f, ay = 0.f, bx = 0.f, by = 0.f;
      for (; e + 12 < e1; e += 16) {
        int s0 = __builtin_nontemporal_load(esrc + e);
        int s1 = __builtin_nontemporal_load(esrc + e + 4);
        int s2 = __builtin_nontemporal_load(esrc + e + 8);
        int s3 = __builtin_nontemporal_load(esrc + e + 12);
        float2 h0 = __half22float2(hp[((size_t)s0 << 5) + fo]);
        float2 h1 = __half22float2(hp[((size_t)s1 << 5) + fo]);
        float2 h2 = __half22float2(hp[((size_t)s2 << 5) + fo]);
        float2 h3 = __half22float2(hp[((size_t)s3 << 5) + fo]);
        ax += h0.x; ay += h0.y; bx += h1.x; by += h1.y;
        ax += h2.x; ay += h2.y; bx += h3.x; by += h3.y;
      }
      for (; e + 4 < e1; e += 8) {
        int s0 = __builtin_nontemporal_load(esrc + e);
        int s1 = __builtin_nontemporal_load(esrc + e + 4);
        float2 h0 = __half22float2(hp[((size_t)s0 << 5) + fo]);
        float2 h1 = __half22float2(hp[((size_t)s1 << 5) + fo]);
        ax += h0.x; ay += h0.y; bx += h1.x; by += h1.y;
      }
      if (e < e1) {
        int s0 = __builtin_nontemporal_load(esrc + e);
        float2 h0 = __half22float2(hp[((size_t)s0 << 5) + fo]);
        ax += h0.x; ay += h0.y;
      }
      ax += bx; ay += by;
      ax += __shfl_down(ax, 32); ay += __shfl_down(ay, 32);
      ax += __shfl_down(ax, 16); ay += __shfl_down(ay, 16);
      if (grp == 0) {
        float2 hs = __half22float2(hp[((size_t)gi << 5) + fo]);  // self (scaled)
        __half2 o2 = __floats2half2_rn(di * (ax + hs.x), di * (ay + hs.y));
        __builtin_nontemporal_store(*(unsigned int*)&o2,
            (unsigned int*)((__half2*)out + (((size_t)gi << 5) + fo)));
      }
    }
  }
}

__global__ __launch_bounds__(256) void agg128_bn_xcc_kernel(
    const __half* __restrict__ h, const int* __restrict__ offs,
    const int* __restrict__ offe, const int* __restrict__ esrc,
    const float* __restrict__ dinv,
    const float* __restrict__ bias, const float* __restrict__ gam,
    const float* __restrict__ bet, const float* __restrict__ mean,
    const float* __restrict__ var, __half* __restrict__ out,
    int* __restrict__ cursor, int n) {
  const int slice = xcc_id() & 3;           // 3.2MB slice, XCDs {s, s+4}
  int* cur = cursor + slice;
  const int t = threadIdx.x;
  const int wave = t >> 6, lane = t & 63;
  const int grp = lane >> 4;
  const int fo = slice * 16 + (lane & 15);  // half2 idx within 64-half2 row
  const __half2* hp = (const __half2*)h;

  const int c = fo << 1;                    // BN params hoisted (per-feature)
  const float2 bv = *(const float2*)(bias + c);
  const float2 gv = *(const float2*)(gam + c);
  const float2 bev = *(const float2*)(bet + c);
  const float2 mv = *(const float2*)(mean + c);
  const float2 vv = *(const float2*)(var + c);
  const float sx = gv.x * rsqrtf(vv.x + BN_EPS);
  const float sy = gv.y * rsqrtf(vv.y + BN_EPS);
  __shared__ int sb;

  for (;;) {
    if (t == 0) sb = atomicAdd(cur, 1);
    __syncthreads();
    const int nbase = sb * CHN;
    __syncthreads();
    if (nbase >= n) return;
    const int g0 = nbase + wave * (CHN / 4);
#pragma unroll 1
    for (int w = 0; w < CHN / 4; ++w) {
      const int gi = g0 + w;
      if (gi >= n) break;
      const float di = dinv[gi];
      int e = offs[gi] + grp;
      const int e1 = offe[gi];
      float ax = 0.f, ay = 0.f, bx = 0.f, by = 0.f;
      for (; e + 12 < e1; e += 16) {
        int s0 = __builtin_nontemporal_load(esrc + e);
        int s1 = __builtin_nontemporal_load(esrc + e + 4);
        int s2 = __builtin_nontemporal_load(esrc + e + 8);
        int s3 = __builtin_nontemporal_load(esrc + e + 12);
        float2 h0 = __half22float2(hp[((size_t)s0 << 6) + fo]);
        float2 h1 = __half22float2(hp[((size_t)s1 << 6) + fo]);
        float2 h2 = __half22float2(hp[((size_t)s2 << 6) + fo]);
        float2 h3 = __half22float2(hp[((size_t)s3 << 6) + fo]);
        ax += h0.x; ay += h0.y; bx += h1.x; by += h1.y;
        ax += h2.x; ay += h2.y; bx += h3.x; by += h3.y;
      }
      for (; e + 4 < e1; e += 8) {
        int s0 = __builtin_nontemporal_load(esrc + e);
        int s1 = __builtin_nontemporal_load(esrc + e + 4);
        float2 h0 = __half22float2(hp[((size_t)s0 << 6) + fo]);
        float2 h1 = __half22float2(hp[((size_t)s1 << 6) + fo]);
        ax += h0.x; ay += h0.y; bx += h1.x; by += h1.y;
      }
      if (e < e1) {
        int s0 = __builtin_nontemporal_load(esrc + e);
        float2 h0 = __half22float2(hp[((size_t)s0 << 6) + fo]);
        ax += h0.x; ay += h0.y;
      }
      ax += bx; ay += by;
      ax += __shfl_down(ax, 32); ay += __shfl_down(ay, 32);
      ax += __shfl_down(ax, 16); ay += __shfl_down(ay, 16);
      if (grp == 0) {
        float2 hs = __half22float2(hp[((size_t)gi << 6) + fo]);  // self (scaled)
        float vx = di * (ax + hs.x);
        float vy = di * (ay + hs.y);
        float o0 = fmaxf(fmaf(vx + bv.x - mv.x, sx, bev.x), 0.f);
        float o1 = fmaxf(fmaf(vy + bv.y - mv.y, sy, bev.y), 0.f);
        __half2 o2 = __floats2half2_rn(o0, o1);
        __builtin_nontemporal_store(*(unsigned int*)&o2,
            (unsigned int*)((__half2*)out + (((size_t)gi << 6) + fo)));
      }
    }
  }
}

// ---------------------------------------------------------------------------

static inline size_t alignup(size_t x, size_t a) { return (x + a - 1) & ~(a - 1); }

extern "C" void kernel_launch(void* const* d_in, const int* in_sizes, int n_in,
                              void* d_out, int out_size, void* d_ws, size_t ws_size,
                              hipStream_t stream) {
  const float* x   = (const float*)d_in[0];
  const int*   src = (const int*)d_in[1];
  const int*   dst = (const int*)d_in[2];
  const float* W0  = (const float*)d_in[3];
  const float* b0  = (const float*)d_in[4];
  const float* g0  = (const float*)d_in[5];
  const float* be0 = (const float*)d_in[6];
  const float* m0  = (const float*)d_in[7];
  const float* v0  = (const float*)d_in[8];
  const float* W1  = (const float*)d_in[9];
  const float* b1  = (const float*)d_in[10];
  const float* g1  = (const float*)d_in[11];
  const float* be1 = (const float*)d_in[12];
  const float* m1  = (const float*)d_in[13];
  const float* v1  = (const float*)d_in[14];
  const float* W2  = (const float*)d_in[15];
  const float* b2  = (const float*)d_in[16];
  const float* g2  = (const float*)d_in[17];
  const float* be2 = (const float*)d_in[18];
  const float* m2  = (const float*)d_in[19];
  const float* v2  = (const float*)d_in[20];
  const float* Wm1 = (const float*)d_in[21];
  const float* bm1 = (const float*)d_in[22];
  const float* Wm2 = (const float*)d_in[23];
  const float* bm2 = (const float*)d_in[24];

  const int N = in_sizes[0] / 64;
  const int E = in_sizes[1];

  char* p = (char*)d_ws;
  auto take = [&](size_t bytes) {
    char* r = p;
    p += alignup(bytes, 256);
    return r;
  };
  const int nbk = (N + BK - 1) / BK;    // buckets (98 for N=50000)
  int*    bcursor= (int*)take(NBMAX * 4);
  int*    curs   = (int*)take(64);      // 16 slice cursors (2 + 4 + 4 used)
  int*    offs   = (int*)take((size_t)N * 4);
  int*    offe   = (int*)take((size_t)N * 4);
  float*  dinv   = (float*)take((size_t)N * 4);
  int*    esrc   = (int*)take((size_t)nbk * BCAP * 4);
  int2*   tmp    = (int2*)take((size_t)nbk * BCAP * 8);
  __half* x16    = (__half*)take((size_t)N * 64 * 2);
  __half* aggx16 = (__half*)take((size_t)N * 64 * 2);
  __half* t0     = (__half*)take((size_t)N * 128 * 2);
  __half* t1     = (__half*)take((size_t)N * 128 * 2);
  float*  yout   = (float*)d_out;

  const int TB = 256;
  const int sb = (E + ECH - 1) / ECH;   // scatter blocks
  const int n4 = N * 16;                // float4 count of x
  const int cb = (n4 + 255) / 256;      // cvt blocks

  // --- CSR build (fixed-stride buckets) + fp16 x, 3 dispatches total ---
  hipMemsetAsync(bcursor, 0, NBMAX * 4 + 256, stream);   // bcursor + curs
  scatter_cvt_kernel<<<sb + cb, TB, 0, stream>>>(src, dst, bcursor, tmp,
                                                 x, x16, E, nbk, sb, n4);
  bucket_finalize_kernel<<<nbk, TB, 0, stream>>>(tmp, bcursor, offs, offe,
                                                 dinv, esrc, x16, N);

  const int gemmGrid = (N + 127) / 128;
  const int aggGrid = 2048;             // persistent-ish, 8 blocks/CU

  // --- layer 0 (x16 rows pre-scaled by dinv in finalize; agg is pure sum) ---
  agg64_xcc_kernel<<<aggGrid, TB, 0, stream>>>(x16, offs, offe, esrc, dinv,
                                               aggx16, curs + 0, N);
  mgemm_kernel<64, 128, 3, true><<<gemmGrid, TB, 0, stream>>>(
      aggx16, W0, b0, g0, be0, m0, v0, t0, N);
  // --- layer 1 (GEMM pre-scales rows by dinv via EPI=4; agg sums + BN) ---
  mgemm_kernel<128, 128, 4, true><<<gemmGrid, TB, 0, stream>>>(
      t0, W1, dinv, nullptr, nullptr, nullptr, nullptr, t1, N);
  agg128_bn_xcc_kernel<<<aggGrid, TB, 0, stream>>>(t1, offs, offe, esrc, dinv,
                                                   b1, g1, be1, m1, v1, t0,
                                                   curs + 4, N);
  // --- layer 2 ---
  mgemm_kernel<128, 128, 4, true><<<gemmGrid, TB, 0, stream>>>(
      t0, W2, dinv, nullptr, nullptr, nullptr, nullptr, t1, N);
  agg128_bn_xcc_kernel<<<aggGrid, TB, 0, stream>>>(t1, offs, offe, esrc, dinv,
                                                   b2, g2, be2, m2, v2, t0,
                                                   curs + 8, N);
  // --- fused MLP ---
  mlp_kernel<<<gemmGrid, TB, 0, stream>>>(t0, Wm1, bm1, Wm2, bm2, yout, N);
}

// Round 4
// 590.699 us; speedup vs baseline: 1.0425x; 1.0425x over previous
//
#include <hip/hip_runtime.h>
#include <hip/hip_fp16.h>

#define BN_EPS 1e-5f
#define BK 512        // dst-nodes per bucket (contiguous node range)
#define NBMAX 128
#define ECH 8192      // edges per scatter block
#define BCAP 9216     // fixed per-bucket capacity (mean 8163, sigma~90 -> 11+ sigma)
#define CHN 32        // nodes per cursor grab (8 per wave)

typedef _Float16 half_t;
typedef _Float16 half8 __attribute__((ext_vector_type(8)));
typedef float floatx4 __attribute__((ext_vector_type(4)));

__device__ __forceinline__ int xcc_id() {
  int x;
  asm volatile("s_getreg_b32 %0, hwreg(HW_REG_XCC_ID)" : "=s"(x));
  return x;
}

// ---------------------------------------------------------------------------
// PLANE-MAJOR layout: every N x F fp16 array is stored as F/32 planes of
// [N][32] halfs (64B rows).  elem(row, f) = plane f>>5, offset row*32+(f&31).
// A plane is 3.2MB (N=50k) and is line-disjoint -> one plane fits a 4MB
// per-XCD L2 with slack.  Aggregation slices = planes, pinned to XCDs via
// HW_REG_XCC_ID (rounds 1/3 failed because 64B slices shared 128B lines ->
// 6.4MB line working set > L2; plane granularity fixes exactly that).
// ---------------------------------------------------------------------------

// blocks [0, sb): scatter {src,dst} into bucket-major tmp.
// blocks [sb, ..): fp32 -> fp16 plane-major copy of x.
__global__ __launch_bounds__(256) void scatter_cvt_kernel(
    const int* __restrict__ src, const int* __restrict__ dst,
    int* __restrict__ bcursor, int2* __restrict__ tmp,
    const float* __restrict__ x, __half* __restrict__ x16,
    int E, int nb, int sb, int n4, int nN) {
  const int t = threadIdx.x;
  if (blockIdx.x >= sb) {
    int i = (blockIdx.x - sb) * 256 + t;
    if (i < n4) {
      float4 v = *(const float4*)(x + (size_t)i * 4);
      union { __half h[4]; float2 f; } u;
      u.h[0] = __float2half_rn(v.x);
      u.h[1] = __float2half_rn(v.y);
      u.h[2] = __float2half_rn(v.z);
      u.h[3] = __float2half_rn(v.w);
      int row = i >> 4;            // 16 float4 per 64-feat row
      int f0 = (i & 15) * 4;       // first feature of this float4
      __half* d = x16 + (size_t)(f0 >> 5) * ((size_t)nN * 32)
                      + (size_t)row * 32 + (f0 & 31);
      *(float2*)d = u.f;
    }
    return;
  }
  __shared__ int h[NBMAX];
  for (int i = t; i < nb; i += 256) h[i] = 0;
  __syncthreads();
  const int base = blockIdx.x * ECH;
#pragma unroll 8
  for (int p = 0; p < ECH / 256; ++p) {
    int e = base + p * 256 + t;
    if (e < E) atomicAdd(&h[dst[e] >> 9], 1);
  }
  __syncthreads();
  for (int i = t; i < nb; i += 256) {
    int c = h[i];
    h[i] = c ? (i * BCAP + atomicAdd(&bcursor[i], c)) : 0;  // contiguous run
  }
  __syncthreads();
#pragma unroll 8
  for (int p = 0; p < ECH / 256; ++p) {
    int e = base + p * 256 + t;
    if (e < E) {
      int s = src[e], d = dst[e];
      int pos = atomicAdd(&h[d >> 9], 1);
      tmp[pos] = make_int2(s, d);
    }
  }
}

// One block per bucket: LDS degree count -> local scan -> offs/offe/dinv/esrc.
// Also pre-scales this bucket's x16 rows by dinv[row] (dinv fold for layer 0).
__global__ __launch_bounds__(256) void bucket_finalize_kernel(
    const int2* __restrict__ tmp, const int* __restrict__ bcursor,
    int* __restrict__ offs, int* __restrict__ offe, float* __restrict__ dinv,
    int* __restrict__ esrc, __half* __restrict__ x16, int n) {
  __shared__ int deg[BK];
  __shared__ int cur[BK];
  __shared__ float fdi[BK];
  __shared__ int ts[256];
  const int t = threadIdx.x;
  const int b = blockIdx.x;
  const int nbase = b * BK;
  const int nn = min(BK, n - nbase);
  const int cnt = bcursor[b];
  const int2* tp = tmp + (size_t)b * BCAP;
  for (int i = t; i < nn; i += 256) deg[i] = 0;
  __syncthreads();
  for (int e = t; e < cnt; e += 256)
    atomicAdd(&deg[tp[e].y - nbase], 1);
  __syncthreads();
  // exclusive scan of 512 degrees (thread t handles 2t, 2t+1)
  int d0 = (2 * t < nn) ? deg[2 * t] : 0;
  int d1 = (2 * t + 1 < nn) ? deg[2 * t + 1] : 0;
  ts[t] = d0 + d1;
  __syncthreads();
  for (int o = 1; o < 256; o <<= 1) {
    int v = (t >= o) ? ts[t - o] : 0;
    __syncthreads();
    ts[t] += v;
    __syncthreads();
  }
  int base = b * BCAP + ((t == 0) ? 0 : ts[t - 1]);
  if (2 * t < nn) {
    float di = rsqrtf(1.0f + (float)d0);
    offs[nbase + 2 * t] = base;
    offe[nbase + 2 * t] = base + d0;
    cur[2 * t] = base;
    fdi[2 * t] = di;
    dinv[nbase + 2 * t] = di;
  }
  if (2 * t + 1 < nn) {
    float di = rsqrtf(1.0f + (float)d1);
    offs[nbase + 2 * t + 1] = base + d0;
    offe[nbase + 2 * t + 1] = base + d0 + d1;
    cur[2 * t + 1] = base + d0;
    fdi[2 * t + 1] = di;
    dinv[nbase + 2 * t + 1] = di;
  }
  __syncthreads();
  for (int e = t; e < cnt; e += 256) {
    int2 r = tp[e];
    int pos = atomicAdd(&cur[r.y - nbase], 1);
    esrc[pos] = r.x;
  }
  // pre-scale x16 rows of this bucket by dinv[row] (plane-major: 2 planes,
  // 16 half2 per row per plane)
  __half2* xp = (__half2*)x16;
  const size_t ps2 = (size_t)n * 16;   // plane stride in half2
  for (int i = t; i < nn * 32; i += 256) {
    int nl = i >> 5, q = i & 31;
    size_t idx = (size_t)(q >> 4) * ps2 + (size_t)(nbase + nl) * 16 + (q & 15);
    float2 v = __half22float2(xp[idx]);
    float s = fdi[nl];
    xp[idx] = __floats2half2_rn(v.x * s, v.y * s);
  }
}

// ---------------------------------------------------------------------------
// MFMA fp16 GEMM (fp32 accumulate).  256 thr = 4 waves; 128-row tile.
// X input and half-output are PLANE-MAJOR (planes of 32 feats, stride n*32).
// EPI: 0 none, 1 bias+relu, 2 bias, 3 bias+BN+relu,
//      4 row-scale (bias ptr = per-row dinv; writes dinv[row]*acc).
// ---------------------------------------------------------------------------

template <int FIN, int FOUT, int EPI, bool HALFOUT>
__global__ __launch_bounds__(256) void mgemm_kernel(
    const __half* __restrict__ X, const float* __restrict__ W,
    const float* __restrict__ bias, const float* __restrict__ gam,
    const float* __restrict__ bet, const float* __restrict__ mean,
    const float* __restrict__ var, void* __restrict__ Yv, int n) {
  constexpr int LDK = 72;
  constexpr int NCI = FOUT / 16;
  __shared__ half_t Asm[128 * LDK];
  __shared__ half_t Bsm[FOUT * LDK];

  const int t = threadIdx.x;
  const int wave = t >> 6, lane = t & 63;
  const int quad = lane >> 4, l16 = lane & 15;
  const int rowBase = blockIdx.x * 128;
  const size_t psh = (size_t)n * 32;   // plane stride in halfs

  floatx4 acc[2][NCI];
#pragma unroll
  for (int i = 0; i < 2; ++i)
#pragma unroll
    for (int ci = 0; ci < NCI; ++ci) acc[i][ci] = (floatx4){0.f, 0.f, 0.f, 0.f};

  for (int kc = 0; kc < FIN; kc += 64) {
    __syncthreads();
    {
      const int kq = t & 15, m0 = t >> 4;
      const int col = kc + kq * 4;
      const __half* Xp = X + (size_t)(col >> 5) * psh + (col & 31);
#pragma unroll
      for (int p = 0; p < 8; ++p) {
        int m = p * 16 + m0;
        int row = rowBase + m;
        uint2 v = make_uint2(0u, 0u);
        if (row < n) v = *(const uint2*)(Xp + (size_t)row * 32);
        *(uint2*)&Asm[m * LDK + kq * 4] = v;
      }
    }
    {
#pragma unroll
      for (int c0 = 0; c0 < FOUT * 16; c0 += 256) {
        int c = c0 + t;
        int nn = c % FOUT;
        int kg = (c / FOUT) * 4;
        const float* wp = W + (size_t)(kc + kg) * FOUT + nn;
        half_t* d = &Bsm[nn * LDK + kg];
        d[0] = (half_t)wp[0];
        d[1] = (half_t)wp[FOUT];
        d[2] = (half_t)wp[2 * FOUT];
        d[3] = (half_t)wp[3 * FOUT];
      }
    }
    __syncthreads();
#pragma unroll
    for (int kk = 0; kk < 2; ++kk) {
      half8 a0 = *(const half8*)&Asm[(wave * 32 + l16) * LDK + kk * 32 + quad * 8];
      half8 a1 = *(const half8*)&Asm[(wave * 32 + 16 + l16) * LDK + kk * 32 + quad * 8];
#pragma unroll
      for (int ci = 0; ci < NCI; ++ci) {
        half8 b = *(const half8*)&Bsm[(ci * 16 + l16) * LDK + kk * 32 + quad * 8];
        acc[0][ci] = __builtin_amdgcn_mfma_f32_16x16x32_f16(a0, b, acc[0][ci], 0, 0, 0);
        acc[1][ci] = __builtin_amdgcn_mfma_f32_16x16x32_f16(a1, b, acc[1][ci], 0, 0, 0);
      }
    }
  }

  float sc[NCI], sh[NCI];
#pragma unroll
  for (int ci = 0; ci < NCI; ++ci) {
    int col = ci * 16 + l16;
    if constexpr (EPI == 3) {
      float s = gam[col] * rsqrtf(var[col] + BN_EPS);
      sc[ci] = s;
      sh[ci] = (bias[col] - mean[col]) * s + bet[col];
    } else if constexpr (EPI == 1 || EPI == 2) {
      sc[ci] = 1.f;
      sh[ci] = bias[col];
    } else {
      sc[ci] = 1.f;
      sh[ci] = 0.f;
    }
  }
  float rs[2][4];
  if constexpr (EPI == 4) {
#pragma unroll
    for (int ri = 0; ri < 2; ++ri)
#pragma unroll
      for (int r = 0; r < 4; ++r) {
        int row = rowBase + wave * 32 + ri * 16 + quad * 4 + r;
        rs[ri][r] = (row < n) ? bias[row] : 0.f;   // bias ptr = dinv (per-row)
      }
  }
#pragma unroll
  for (int ri = 0; ri < 2; ++ri)
#pragma unroll
    for (int ci = 0; ci < NCI; ++ci) {
      int col = ci * 16 + l16;
#pragma unroll
      for (int r = 0; r < 4; ++r) {
        int row = rowBase + wave * 32 + ri * 16 + quad * 4 + r;
        if (row < n) {
          float v = acc[ri][ci][r];
          if constexpr (EPI == 4) v *= rs[ri][r];
          if constexpr (EPI == 1 || EPI == 2 || EPI == 3) v = fmaf(v, sc[ci], sh[ci]);
          if constexpr (EPI == 1 || EPI == 3) v = fmaxf(v, 0.f);
          if constexpr (HALFOUT)
            ((half_t*)Yv)[(size_t)(col >> 5) * psh + (size_t)row * 32 + (col & 31)] = (half_t)v;
          else
            ((float*)Yv)[(size_t)row * FOUT + col] = v;
        }
      }
    }
}

// ---------------------------------------------------------------------------
// Fused MLP: Y = relu(X@W1+b1)@W2 + b2.  X is plane-major; Y row-major fp32.
// ---------------------------------------------------------------------------

__global__ __launch_bounds__(256) void mlp_kernel(
    const __half* __restrict__ X, const float* __restrict__ W1,
    const float* __restrict__ b1f, const float* __restrict__ W2,
    const float* __restrict__ b2f, float* __restrict__ Y, int n) {
  constexpr int LDK = 72;
  constexpr int LDK2 = 136;
  __shared__ half_t smem[(128 + 64) * LDK2];
  half_t* As1 = smem;
  half_t* Bs1 = smem + 128 * LDK;
  half_t* As2 = smem;
  half_t* Bs2 = smem + 128 * LDK2;

  const int t = threadIdx.x;
  const int wave = t >> 6, lane = t & 63;
  const int quad = lane >> 4, l16 = lane & 15;
  const int rowBase = blockIdx.x * 128;
  const size_t psh = (size_t)n * 32;

  floatx4 acc[2][8];
#pragma unroll
  for (int i = 0; i < 2; ++i)
#pragma unroll
    for (int ci = 0; ci < 8; ++ci) acc[i][ci] = (floatx4){0.f, 0.f, 0.f, 0.f};

  for (int kc = 0; kc < 128; kc += 64) {
    __syncthreads();
    {
      const int kq = t & 15, m0 = t >> 4;
      const int col = kc + kq * 4;
      const __half* Xp = X + (size_t)(col >> 5) * psh + (col & 31);
#pragma unroll
      for (int p = 0; p < 8; ++p) {
        int m = p * 16 + m0;
        int row = rowBase + m;
        uint2 v = make_uint2(0u, 0u);
        if (row < n) v = *(const uint2*)(Xp + (size_t)row * 32);
        *(uint2*)&As1[m * LDK + kq * 4] = v;
      }
    }
    {
#pragma unroll
      for (int c0 = 0; c0 < 128 * 16; c0 += 256) {
        int c = c0 + t;
        int nn = c & 127;
        int kg = (c >> 7) << 2;
        const float* wp = W1 + (size_t)(kc + kg) * 128 + nn;
        half_t* d = &Bs1[nn * LDK + kg];
        d[0] = (half_t)wp[0];
        d[1] = (half_t)wp[128];
        d[2] = (half_t)wp[256];
        d[3] = (half_t)wp[384];
      }
    }
    __syncthreads();
#pragma unroll
    for (int kk = 0; kk < 2; ++kk) {
      half8 a0 = *(const half8*)&As1[(wave * 32 + l16) * LDK + kk * 32 + quad * 8];
      half8 a1 = *(const half8*)&As1[(wave * 32 + 16 + l16) * LDK + kk * 32 + quad * 8];
#pragma unroll
      for (int ci = 0; ci < 8; ++ci) {
        half8 b = *(const half8*)&Bs1[(ci * 16 + l16) * LDK + kk * 32 + quad * 8];
        acc[0][ci] = __builtin_amdgcn_mfma_f32_16x16x32_f16(a0, b, acc[0][ci], 0, 0, 0);
        acc[1][ci] = __builtin_amdgcn_mfma_f32_16x16x32_f16(a1, b, acc[1][ci], 0, 0, 0);
      }
    }
  }
  __syncthreads();

#pragma unroll
  for (int ri = 0; ri < 2; ++ri)
#pragma unroll
    for (int ci = 0; ci < 8; ++ci) {
      int col = ci * 16 + l16;
      float bz = b1f[col];
#pragma unroll
      for (int r = 0; r < 4; ++r) {
        int m = wave * 32 + ri * 16 + quad * 4 + r;
        As2[m * LDK2 + col] = (half_t)fmaxf(acc[ri][ci][r] + bz, 0.f);
      }
    }
  {
#pragma unroll
    for (int c0 = 0; c0 < 64 * 32; c0 += 256) {
      int c = c0 + t;
      int nn = c & 63;
      int kg = (c >> 6) << 2;
      const float* wp = W2 + (size_t)kg * 64 + nn;
      half_t* d = &Bs2[nn * LDK2 + kg];
      d[0] = (half_t)wp[0];
      d[1] = (half_t)wp[64];
      d[2] = (half_t)wp[128];
      d[3] = (half_t)wp[192];
    }
  }
  __syncthreads();

  floatx4 acc2[2][4];
#pragma unroll
  for (int i = 0; i < 2; ++i)
#pragma unroll
    for (int ci = 0; ci < 4; ++ci) acc2[i][ci] = (floatx4){0.f, 0.f, 0.f, 0.f};
#pragma unroll
  for (int kk = 0; kk < 4; ++kk) {
    half8 a0 = *(const half8*)&As2[(wave * 32 + l16) * LDK2 + kk * 32 + quad * 8];
    half8 a1 = *(const half8*)&As2[(wave * 32 + 16 + l16) * LDK2 + kk * 32 + quad * 8];
#pragma unroll
    for (int ci = 0; ci < 4; ++ci) {
      half8 b = *(const half8*)&Bs2[(ci * 16 + l16) * LDK2 + kk * 32 + quad * 8];
      acc2[0][ci] = __builtin_amdgcn_mfma_f32_16x16x32_f16(a0, b, acc2[0][ci], 0, 0, 0);
      acc2[1][ci] = __builtin_amdgcn_mfma_f32_16x16x32_f16(a1, b, acc2[1][ci], 0, 0, 0);
    }
  }
#pragma unroll
  for (int ri = 0; ri < 2; ++ri)
#pragma unroll
    for (int ci = 0; ci < 4; ++ci) {
      int col = ci * 16 + l16;
      float bz = b2f[col];
#pragma unroll
      for (int r = 0; r < 4; ++r) {
        int row = rowBase + wave * 32 + ri * 16 + quad * 4 + r;
        if (row < n) Y[(size_t)row * 64 + col] = acc2[ri][ci][r] + bz;
      }
    }
}

// ---------------------------------------------------------------------------
// Plane-sliced XCC-pinned aggregations.  slice == plane (line-disjoint
// 3.2MB < 4MB per-XCD L2).  Block reads its XCD id; per-slice cursors hand
// out disjoint CHN-node chunks.  One wave per node; the 4 16-lane groups
// gather different edges' 64B plane rows (256B/instr); shfl reduce.
// Pure sums: dinv folded upstream (finalize for x16, GEMM EPI=4 for t1).
// esrc/out are nontemporal to keep the hot plane resident.
// ---------------------------------------------------------------------------

__global__ __launch_bounds__(256) void agg64_xcc_kernel(
    const __half* __restrict__ h, const int* __restrict__ offs,
    const int* __restrict__ offe, const int* __restrict__ esrc,
    const float* __restrict__ dinv, __half* __restrict__ out,
    int* __restrict__ cursor, int n) {
  const int slice = xcc_id() & 1;           // plane 0/1, 4 XCDs per slice
  int* cur = cursor + slice;
  const int t = threadIdx.x;
  const int wave = t >> 6, lane = t & 63;
  const int grp = lane >> 4, l16 = lane & 15;
  const size_t pb = (size_t)slice * ((size_t)n * 16);   // plane base (half2)
  const __half2* hp = (const __half2*)h + pb;
  __half2* op = (__half2*)out + pb;
  __shared__ int sb;

  for (;;) {
    if (t == 0) sb = atomicAdd(cur, 1);
    __syncthreads();
    const int nbase = sb * CHN;
    __syncthreads();
    if (nbase >= n) return;
    const int g0 = nbase + wave * (CHN / 4);
#pragma unroll 1
    for (int w = 0; w < CHN / 4; ++w) {
      const int gi = g0 + w;
      if (gi >= n) break;
      const float di = dinv[gi];
      int e = offs[gi] + grp;
      const int e1 = offe[gi];
      float ax = 0.f, ay = 0.f, bx = 0.f, by = 0.f;
      for (; e + 4 < e1; e += 8) {
        int s0 = __builtin_nontemporal_load(esrc + e);
        int s1 = __builtin_nontemporal_load(esrc + e + 4);
        float2 h0 = __half22float2(hp[(size_t)s0 * 16 + l16]);
        float2 h1 = __half22float2(hp[(size_t)s1 * 16 + l16]);
        ax += h0.x; ay += h0.y; bx += h1.x; by += h1.y;
      }
      if (e < e1) {
        int s0 = __builtin_nontemporal_load(esrc + e);
        float2 h0 = __half22float2(hp[(size_t)s0 * 16 + l16]);
        ax += h0.x; ay += h0.y;
      }
      ax += bx; ay += by;
      ax += __shfl_down(ax, 32); ay += __shfl_down(ay, 32);
      ax += __shfl_down(ax, 16); ay += __shfl_down(ay, 16);
      if (grp == 0) {
        float2 hs = __half22float2(hp[(size_t)gi * 16 + l16]);  // self (scaled)
        __half2 o2 = __floats2half2_rn(di * (ax + hs.x), di * (ay + hs.y));
        __builtin_nontemporal_store(*(unsigned int*)&o2,
            (unsigned int*)(op + (size_t)gi * 16 + l16));
      }
    }
  }
}

__global__ __launch_bounds__(256) void agg128_bn_xcc_kernel(
    const __half* __restrict__ h, const int* __restrict__ offs,
    const int* __restrict__ offe, const int* __restrict__ esrc,
    const float* __restrict__ dinv,
    const float* __restrict__ bias, const float* __restrict__ gam,
    const float* __restrict__ bet, const float* __restrict__ mean,
    const float* __restrict__ var, __half* __restrict__ out,
    int* __restrict__ cursor, int n) {
  const int slice = xcc_id() & 3;           // plane 0..3, XCDs {s, s+4}
  int* cur = cursor + slice;
  const int t = threadIdx.x;
  const int wave = t >> 6, lane = t & 63;
  const int grp = lane >> 4, l16 = lane & 15;
  const size_t pb = (size_t)slice * ((size_t)n * 16);   // plane base (half2)
  const __half2* hp = (const __half2*)h + pb;
  __half2* op = (__half2*)out + pb;

  const int c = slice * 32 + l16 * 2;       // global feature index (BN params)
  const float2 bv = *(const float2*)(bias + c);
  const float2 gv = *(const float2*)(gam + c);
  const float2 bev = *(const float2*)(bet + c);
  const float2 mv = *(const float2*)(mean + c);
  const float2 vv = *(const float2*)(var + c);
  const float sx = gv.x * rsqrtf(vv.x + BN_EPS);
  const float sy = gv.y * rsqrtf(vv.y + BN_EPS);
  __shared__ int sb;

  for (;;) {
    if (t == 0) sb = atomicAdd(cur, 1);
    __syncthreads();
    const int nbase = sb * CHN;
    __syncthreads();
    if (nbase >= n) return;
    const int g0 = nbase + wave * (CHN / 4);
#pragma unroll 1
    for (int w = 0; w < CHN / 4; ++w) {
      const int gi = g0 + w;
      if (gi >= n) break;
      const float di = dinv[gi];
      int e = offs[gi] + grp;
      const int e1 = offe[gi];
      float ax = 0.f, ay = 0.f, bx = 0.f, by = 0.f;
      for (; e + 4 < e1; e += 8) {
        int s0 = __builtin_nontemporal_load(esrc + e);
        int s1 = __builtin_nontemporal_load(esrc + e + 4);
        float2 h0 = __half22float2(hp[(size_t)s0 * 16 + l16]);
        float2 h1 = __half22float2(hp[(size_t)s1 * 16 + l16]);
        ax += h0.x; ay += h0.y; bx += h1.x; by += h1.y;
      }
      if (e < e1) {
        int s0 = __builtin_nontemporal_load(esrc + e);
        float2 h0 = __half22float2(hp[(size_t)s0 * 16 + l16]);
        ax += h0.x; ay += h0.y;
      }
      ax += bx; ay += by;
      ax += __shfl_down(ax, 32); ay += __shfl_down(ay, 32);
      ax += __shfl_down(ax, 16); ay += __shfl_down(ay, 16);
      if (grp == 0) {
        float2 hs = __half22float2(hp[(size_t)gi * 16 + l16]);  // self (scaled)
        float vx = di * (ax + hs.x);
        float vy = di * (ay + hs.y);
        float o0 = fmaxf(fmaf(vx + bv.x - mv.x, sx, bev.x), 0.f);
        float o1 = fmaxf(fmaf(vy + bv.y - mv.y, sy, bev.y), 0.f);
        __half2 o2 = __floats2half2_rn(o0, o1);
        __builtin_nontemporal_store(*(unsigned int*)&o2,
            (unsigned int*)(op + (size_t)gi * 16 + l16));
      }
    }
  }
}

// ---------------------------------------------------------------------------

static inline size_t alignup(size_t x, size_t a) { return (x + a - 1) & ~(a - 1); }

extern "C" void kernel_launch(void* const* d_in, const int* in_sizes, int n_in,
                              void* d_out, int out_size, void* d_ws, size_t ws_size,
                              hipStream_t stream) {
  const float* x   = (const float*)d_in[0];
  const int*   src = (const int*)d_in[1];
  const int*   dst = (const int*)d_in[2];
  const float* W0  = (const float*)d_in[3];
  const float* b0  = (const float*)d_in[4];
  const float* g0  = (const float*)d_in[5];
  const float* be0 = (const float*)d_in[6];
  const float* m0  = (const float*)d_in[7];
  const float* v0  = (const float*)d_in[8];
  const float* W1  = (const float*)d_in[9];
  const float* b1  = (const float*)d_in[10];
  const float* g1  = (const float*)d_in[11];
  const float* be1 = (const float*)d_in[12];
  const float* m1  = (const float*)d_in[13];
  const float* v1  = (const float*)d_in[14];
  const float* W2  = (const float*)d_in[15];
  const float* b2  = (const float*)d_in[16];
  const float* g2  = (const float*)d_in[17];
  const float* be2 = (const float*)d_in[18];
  const float* m2  = (const float*)d_in[19];
  const float* v2  = (const float*)d_in[20];
  const float* Wm1 = (const float*)d_in[21];
  const float* bm1 = (const float*)d_in[22];
  const float* Wm2 = (const float*)d_in[23];
  const float* bm2 = (const float*)d_in[24];

  const int N = in_sizes[0] / 64;
  const int E = in_sizes[1];

  char* p = (char*)d_ws;
  auto take = [&](size_t bytes) {
    char* r = p;
    p += alignup(bytes, 256);
    return r;
  };
  const int nbk = (N + BK - 1) / BK;    // buckets (98 for N=50000)
  int*    bcursor= (int*)take(NBMAX * 4);
  int*    curs   = (int*)take(64);      // slice cursors (2 + 4 + 4 used)
  int*    offs   = (int*)take((size_t)N * 4);
  int*    offe   = (int*)take((size_t)N * 4);
  float*  dinv   = (float*)take((size_t)N * 4);
  int*    esrc   = (int*)take((size_t)nbk * BCAP * 4);
  int2*   tmp    = (int2*)take((size_t)nbk * BCAP * 8);
  __half* x16    = (__half*)take((size_t)N * 64 * 2);
  __half* aggx16 = (__half*)take((size_t)N * 64 * 2);
  __half* t0     = (__half*)take((size_t)N * 128 * 2);
  __half* t1     = (__half*)take((size_t)N * 128 * 2);
  float*  yout   = (float*)d_out;

  const int TB = 256;
  const int sb = (E + ECH - 1) / ECH;   // scatter blocks
  const int n4 = N * 16;                // float4 count of x
  const int cb = (n4 + 255) / 256;      // cvt blocks

  // --- CSR build (fixed-stride buckets) + fp16 plane-major x ---
  hipMemsetAsync(bcursor, 0, NBMAX * 4 + 256, stream);   // bcursor + curs
  scatter_cvt_kernel<<<sb + cb, TB, 0, stream>>>(src, dst, bcursor, tmp,
                                                 x, x16, E, nbk, sb, n4, N);
  bucket_finalize_kernel<<<nbk, TB, 0, stream>>>(tmp, bcursor, offs, offe,
                                                 dinv, esrc, x16, N);

  const int gemmGrid = (N + 127) / 128;
  const int aggGrid = 2048;             // persistent, 8 blocks/CU

  // --- layer 0 (x16 pre-scaled by dinv in finalize; agg is pure sum) ---
  agg64_xcc_kernel<<<aggGrid, TB, 0, stream>>>(x16, offs, offe, esrc, dinv,
                                               aggx16, curs + 0, N);
  mgemm_kernel<64, 128, 3, true><<<gemmGrid, TB, 0, stream>>>(
      aggx16, W0, b0, g0, be0, m0, v0, t0, N);
  // --- layer 1 (GEMM pre-scales rows by dinv via EPI=4; agg sums + BN) ---
  mgemm_kernel<128, 128, 4, true><<<gemmGrid, TB, 0, stream>>>(
      t0, W1, dinv, nullptr, nullptr, nullptr, nullptr, t1, N);
  agg128_bn_xcc_kernel<<<aggGrid, TB, 0, stream>>>(t1, offs, offe, esrc, dinv,
                                                   b1, g1, be1, m1, v1, t0,
                                                   curs + 4, N);
  // --- layer 2 ---
  mgemm_kernel<128, 128, 4, true><<<gemmGrid, TB, 0, stream>>>(
      t0, W2, dinv, nullptr, nullptr, nullptr, nullptr, t1, N);
  agg128_bn_xcc_kernel<<<aggGrid, TB, 0, stream>>>(t1, offs, offe, esrc, dinv,
                                                   b2, g2, be2, m2, v2, t0,
                                                   curs + 8, N);
  // --- fused MLP ---
  mlp_kernel<<<gemmGrid, TB, 0, stream>>>(t0, Wm1, bm1, Wm2, bm2, yout, N);
}

// Round 5
// 336.690 us; speedup vs baseline: 1.8291x; 1.7544x over previous
//
#include <hip/hip_runtime.h>
#include <hip/hip_fp16.h>

#define BN_EPS 1e-5f
#define BK 512        // dst-nodes per bucket (contiguous node range)
#define NBMAX 128
#define ECH 8192      // edges per scatter block
#define BCAP 9216     // fixed per-bucket capacity (mean 8163, sigma~90 -> 11+ sigma)

typedef _Float16 half_t;
typedef _Float16 half8 __attribute__((ext_vector_type(8)));
typedef float floatx4 __attribute__((ext_vector_type(4)));

// ---------------------------------------------------------------------------
// Preprocess, fixed-stride buckets: bucket b owns tmp/esrc[b*BCAP ..). No
// global histogram or scan passes; per-bucket cursors reserve runs directly.
// CSR is strided (gaps between buckets) -> aggs use explicit offs/offe.
// ---------------------------------------------------------------------------

// blocks [0, sb): scatter {src,dst} into bucket-major tmp (~670B runs/bucket).
// blocks [sb, ..): fp32 -> fp16 copy of x (independent work, merged dispatch).
__global__ __launch_bounds__(256) void scatter_cvt_kernel(
    const int* __restrict__ src, const int* __restrict__ dst,
    int* __restrict__ bcursor, int2* __restrict__ tmp,
    const float* __restrict__ x, __half* __restrict__ x16,
    int E, int nb, int sb, int n4) {
  const int t = threadIdx.x;
  if (blockIdx.x >= sb) {
    int i = (blockIdx.x - sb) * 256 + t;
    if (i < n4) {
      float4 v = *(const float4*)(x + (size_t)i * 4);
      union { __half h[4]; float2 f; } u;
      u.h[0] = __float2half_rn(v.x);
      u.h[1] = __float2half_rn(v.y);
      u.h[2] = __float2half_rn(v.z);
      u.h[3] = __float2half_rn(v.w);
      *(float2*)(x16 + (size_t)i * 4) = u.f;
    }
    return;
  }
  __shared__ int h[NBMAX];
  for (int i = t; i < nb; i += 256) h[i] = 0;
  __syncthreads();
  const int base = blockIdx.x * ECH;
#pragma unroll 8
  for (int p = 0; p < ECH / 256; ++p) {
    int e = base + p * 256 + t;
    if (e < E) atomicAdd(&h[dst[e] >> 9], 1);
  }
  __syncthreads();
  for (int i = t; i < nb; i += 256) {
    int c = h[i];
    h[i] = c ? (i * BCAP + atomicAdd(&bcursor[i], c)) : 0;  // contiguous run
  }
  __syncthreads();
#pragma unroll 8
  for (int p = 0; p < ECH / 256; ++p) {
    int e = base + p * 256 + t;
    if (e < E) {
      int s = src[e], d = dst[e];
      int pos = atomicAdd(&h[d >> 9], 1);
      tmp[pos] = make_int2(s, d);
    }
  }
}

// One block per bucket: LDS degree count -> local scan -> offs/offe/dinv/esrc.
// Also pre-scales this bucket's x16 rows by dinv[row] (dinv-fold for layer 0:
// agg64 then computes out = di * (sum_e x16'[src_e] + x16'[gi]) with no
// per-edge dinv lookup).
__global__ __launch_bounds__(256) void bucket_finalize_kernel(
    const int2* __restrict__ tmp, const int* __restrict__ bcursor,
    int* __restrict__ offs, int* __restrict__ offe, float* __restrict__ dinv,
    int* __restrict__ esrc, __half* __restrict__ x16, int n) {
  __shared__ int deg[BK];
  __shared__ int cur[BK];
  __shared__ float fdi[BK];
  __shared__ int ts[256];
  const int t = threadIdx.x;
  const int b = blockIdx.x;
  const int nbase = b * BK;
  const int nn = min(BK, n - nbase);
  const int cnt = bcursor[b];
  const int2* tp = tmp + (size_t)b * BCAP;
  for (int i = t; i < nn; i += 256) deg[i] = 0;
  __syncthreads();
  for (int e = t; e < cnt; e += 256)
    atomicAdd(&deg[tp[e].y - nbase], 1);
  __syncthreads();
  // exclusive scan of 512 degrees (thread t handles 2t, 2t+1)
  int d0 = (2 * t < nn) ? deg[2 * t] : 0;
  int d1 = (2 * t + 1 < nn) ? deg[2 * t + 1] : 0;
  ts[t] = d0 + d1;
  __syncthreads();
  for (int o = 1; o < 256; o <<= 1) {
    int v = (t >= o) ? ts[t - o] : 0;
    __syncthreads();
    ts[t] += v;
    __syncthreads();
  }
  int base = b * BCAP + ((t == 0) ? 0 : ts[t - 1]);
  if (2 * t < nn) {
    float di = rsqrtf(1.0f + (float)d0);
    offs[nbase + 2 * t] = base;
    offe[nbase + 2 * t] = base + d0;
    cur[2 * t] = base;
    fdi[2 * t] = di;
    dinv[nbase + 2 * t] = di;
  }
  if (2 * t + 1 < nn) {
    float di = rsqrtf(1.0f + (float)d1);
    offs[nbase + 2 * t + 1] = base + d0;
    offe[nbase + 2 * t + 1] = base + d0 + d1;
    cur[2 * t + 1] = base + d0;
    fdi[2 * t + 1] = di;
    dinv[nbase + 2 * t + 1] = di;
  }
  __syncthreads();
  for (int e = t; e < cnt; e += 256) {
    int2 r = tp[e];
    int pos = atomicAdd(&cur[r.y - nbase], 1);
    esrc[pos] = r.x;
  }
  // pre-scale x16 rows of this bucket by dinv[row] (32 half2 per row)
  __half2* xp = (__half2*)x16;
  for (int i = t; i < nn * 32; i += 256) {
    int nl = i >> 5;
    size_t idx = (((size_t)(nbase + nl)) << 5) + (i & 31);
    float2 v = __half22float2(xp[idx]);
    float s = fdi[nl];
    xp[idx] = __floats2half2_rn(v.x * s, v.y * s);
  }
}

// ---------------------------------------------------------------------------
// MFMA fp16 GEMM (fp32 accumulate).  256 thr = 4 waves; 128-row tile.
// Frag layouts (m89/m120): A[m=lane&15][k=quad*8+j]; B[k][n=lane&15];
// C/D row=quad*4+reg, col=lane&15.  LDS stride 72 halfs (2-way = free).
// EPI: 0 none, 1 bias+relu, 2 bias, 3 bias+BN+relu,
//      4 row-scale (bias ptr = per-row dinv; writes dinv[row]*acc).
// ---------------------------------------------------------------------------

template <int FIN, int FOUT, int EPI, bool HALFOUT>
__global__ __launch_bounds__(256) void mgemm_kernel(
    const __half* __restrict__ X, const float* __restrict__ W,
    const float* __restrict__ bias, const float* __restrict__ gam,
    const float* __restrict__ bet, const float* __restrict__ mean,
    const float* __restrict__ var, void* __restrict__ Yv, int n) {
  constexpr int LDK = 72;
  constexpr int NCI = FOUT / 16;
  __shared__ half_t Asm[128 * LDK];
  __shared__ half_t Bsm[FOUT * LDK];

  const int t = threadIdx.x;
  const int wave = t >> 6, lane = t & 63;
  const int quad = lane >> 4, l16 = lane & 15;
  const int rowBase = blockIdx.x * 128;

  floatx4 acc[2][NCI];
#pragma unroll
  for (int i = 0; i < 2; ++i)
#pragma unroll
    for (int ci = 0; ci < NCI; ++ci) acc[i][ci] = (floatx4){0.f, 0.f, 0.f, 0.f};

  for (int kc = 0; kc < FIN; kc += 64) {
    __syncthreads();
    {
      const int kq = t & 15, m0 = t >> 4;
#pragma unroll
      for (int p = 0; p < 8; ++p) {
        int m = p * 16 + m0;
        int row = rowBase + m;
        uint2 v = make_uint2(0u, 0u);
        if (row < n) v = *(const uint2*)(X + (size_t)row * FIN + kc + kq * 4);
        *(uint2*)&Asm[m * LDK + kq * 4] = v;
      }
    }
    {
#pragma unroll
      for (int c0 = 0; c0 < FOUT * 16; c0 += 256) {
        int c = c0 + t;
        int nn = c % FOUT;
        int kg = (c / FOUT) * 4;
        const float* wp = W + (size_t)(kc + kg) * FOUT + nn;
        half_t* d = &Bsm[nn * LDK + kg];
        d[0] = (half_t)wp[0];
        d[1] = (half_t)wp[FOUT];
        d[2] = (half_t)wp[2 * FOUT];
        d[3] = (half_t)wp[3 * FOUT];
      }
    }
    __syncthreads();
#pragma unroll
    for (int kk = 0; kk < 2; ++kk) {
      half8 a0 = *(const half8*)&Asm[(wave * 32 + l16) * LDK + kk * 32 + quad * 8];
      half8 a1 = *(const half8*)&Asm[(wave * 32 + 16 + l16) * LDK + kk * 32 + quad * 8];
#pragma unroll
      for (int ci = 0; ci < NCI; ++ci) {
        half8 b = *(const half8*)&Bsm[(ci * 16 + l16) * LDK + kk * 32 + quad * 8];
        acc[0][ci] = __builtin_amdgcn_mfma_f32_16x16x32_f16(a0, b, acc[0][ci], 0, 0, 0);
        acc[1][ci] = __builtin_amdgcn_mfma_f32_16x16x32_f16(a1, b, acc[1][ci], 0, 0, 0);
      }
    }
  }

  float sc[NCI], sh[NCI];
#pragma unroll
  for (int ci = 0; ci < NCI; ++ci) {
    int col = ci * 16 + l16;
    if constexpr (EPI == 3) {
      float s = gam[col] * rsqrtf(var[col] + BN_EPS);
      sc[ci] = s;
      sh[ci] = (bias[col] - mean[col]) * s + bet[col];
    } else if constexpr (EPI == 1 || EPI == 2) {
      sc[ci] = 1.f;
      sh[ci] = bias[col];
    } else {
      sc[ci] = 1.f;
      sh[ci] = 0.f;
    }
  }
  float rs[2][4];
  if constexpr (EPI == 4) {
#pragma unroll
    for (int ri = 0; ri < 2; ++ri)
#pragma unroll
      for (int r = 0; r < 4; ++r) {
        int row = rowBase + wave * 32 + ri * 16 + quad * 4 + r;
        rs[ri][r] = (row < n) ? bias[row] : 0.f;   // bias ptr = dinv (per-row)
      }
  }
#pragma unroll
  for (int ri = 0; ri < 2; ++ri)
#pragma unroll
    for (int ci = 0; ci < NCI; ++ci) {
      int col = ci * 16 + l16;
#pragma unroll
      for (int r = 0; r < 4; ++r) {
        int row = rowBase + wave * 32 + ri * 16 + quad * 4 + r;
        if (row < n) {
          float v = acc[ri][ci][r];
          if constexpr (EPI == 4) v *= rs[ri][r];
          if constexpr (EPI == 1 || EPI == 2 || EPI == 3) v = fmaf(v, sc[ci], sh[ci]);
          if constexpr (EPI == 1 || EPI == 3) v = fmaxf(v, 0.f);
          if constexpr (HALFOUT)
            ((half_t*)Yv)[(size_t)row * FOUT + col] = (half_t)v;
          else
            ((float*)Yv)[(size_t)row * FOUT + col] = v;
        }
      }
    }
}

// ---------------------------------------------------------------------------
// Fused MLP: Y = relu(X@W1+b1)@W2 + b2.  H kept in LDS (fp16, stride 136).
// ---------------------------------------------------------------------------

__global__ __launch_bounds__(256) void mlp_kernel(
    const __half* __restrict__ X, const float* __restrict__ W1,
    const float* __restrict__ b1f, const float* __restrict__ W2,
    const float* __restrict__ b2f, float* __restrict__ Y, int n) {
  constexpr int LDK = 72;
  constexpr int LDK2 = 136;
  __shared__ half_t smem[(128 + 64) * LDK2];
  half_t* As1 = smem;
  half_t* Bs1 = smem + 128 * LDK;
  half_t* As2 = smem;
  half_t* Bs2 = smem + 128 * LDK2;

  const int t = threadIdx.x;
  const int wave = t >> 6, lane = t & 63;
  const int quad = lane >> 4, l16 = lane & 15;
  const int rowBase = blockIdx.x * 128;

  floatx4 acc[2][8];
#pragma unroll
  for (int i = 0; i < 2; ++i)
#pragma unroll
    for (int ci = 0; ci < 8; ++ci) acc[i][ci] = (floatx4){0.f, 0.f, 0.f, 0.f};

  for (int kc = 0; kc < 128; kc += 64) {
    __syncthreads();
    {
      const int kq = t & 15, m0 = t >> 4;
#pragma unroll
      for (int p = 0; p < 8; ++p) {
        int m = p * 16 + m0;
        int row = rowBase + m;
        uint2 v = make_uint2(0u, 0u);
        if (row < n) v = *(const uint2*)(X + (size_t)row * 128 + kc + kq * 4);
        *(uint2*)&As1[m * LDK + kq * 4] = v;
      }
    }
    {
#pragma unroll
      for (int c0 = 0; c0 < 128 * 16; c0 += 256) {
        int c = c0 + t;
        int nn = c & 127;
        int kg = (c >> 7) << 2;
        const float* wp = W1 + (size_t)(kc + kg) * 128 + nn;
        half_t* d = &Bs1[nn * LDK + kg];
        d[0] = (half_t)wp[0];
        d[1] = (half_t)wp[128];
        d[2] = (half_t)wp[256];
        d[3] = (half_t)wp[384];
      }
    }
    __syncthreads();
#pragma unroll
    for (int kk = 0; kk < 2; ++kk) {
      half8 a0 = *(const half8*)&As1[(wave * 32 + l16) * LDK + kk * 32 + quad * 8];
      half8 a1 = *(const half8*)&As1[(wave * 32 + 16 + l16) * LDK + kk * 32 + quad * 8];
#pragma unroll
      for (int ci = 0; ci < 8; ++ci) {
        half8 b = *(const half8*)&Bs1[(ci * 16 + l16) * LDK + kk * 32 + quad * 8];
        acc[0][ci] = __builtin_amdgcn_mfma_f32_16x16x32_f16(a0, b, acc[0][ci], 0, 0, 0);
        acc[1][ci] = __builtin_amdgcn_mfma_f32_16x16x32_f16(a1, b, acc[1][ci], 0, 0, 0);
      }
    }
  }
  __syncthreads();

#pragma unroll
  for (int ri = 0; ri < 2; ++ri)
#pragma unroll
    for (int ci = 0; ci < 8; ++ci) {
      int col = ci * 16 + l16;
      float bz = b1f[col];
#pragma unroll
      for (int r = 0; r < 4; ++r) {
        int m = wave * 32 + ri * 16 + quad * 4 + r;
        As2[m * LDK2 + col] = (half_t)fmaxf(acc[ri][ci][r] + bz, 0.f);
      }
    }
  {
#pragma unroll
    for (int c0 = 0; c0 < 64 * 32; c0 += 256) {
      int c = c0 + t;
      int nn = c & 63;
      int kg = (c >> 6) << 2;
      const float* wp = W2 + (size_t)kg * 64 + nn;
      half_t* d = &Bs2[nn * LDK2 + kg];
      d[0] = (half_t)wp[0];
      d[1] = (half_t)wp[64];
      d[2] = (half_t)wp[128];
      d[3] = (half_t)wp[192];
    }
  }
  __syncthreads();

  floatx4 acc2[2][4];
#pragma unroll
  for (int i = 0; i < 2; ++i)
#pragma unroll
    for (int ci = 0; ci < 4; ++ci) acc2[i][ci] = (floatx4){0.f, 0.f, 0.f, 0.f};
#pragma unroll
  for (int kk = 0; kk < 4; ++kk) {
    half8 a0 = *(const half8*)&As2[(wave * 32 + l16) * LDK2 + kk * 32 + quad * 8];
    half8 a1 = *(const half8*)&As2[(wave * 32 + 16 + l16) * LDK2 + kk * 32 + quad * 8];
#pragma unroll
    for (int ci = 0; ci < 4; ++ci) {
      half8 b = *(const half8*)&Bs2[(ci * 16 + l16) * LDK2 + kk * 32 + quad * 8];
      acc2[0][ci] = __builtin_amdgcn_mfma_f32_16x16x32_f16(a0, b, acc2[0][ci], 0, 0, 0);
      acc2[1][ci] = __builtin_amdgcn_mfma_f32_16x16x32_f16(a1, b, acc2[1][ci], 0, 0, 0);
    }
  }
#pragma unroll
  for (int ri = 0; ri < 2; ++ri)
#pragma unroll
    for (int ci = 0; ci < 4; ++ci) {
      int col = ci * 16 + l16;
      float bz = b2f[col];
#pragma unroll
      for (int r = 0; r < 4; ++r) {
        int row = rowBase + wave * 32 + ri * 16 + quad * 4 + r;
        if (row < n) Y[(size_t)row * 64 + col] = acc2[ri][ci][r] + bz;
      }
    }
}

// ---------------------------------------------------------------------------
// Aggregations: one wave per node, full 128B/256B row per gather (round-0
// structure, best measured).  Pure sums (dinv folded upstream).  Masked x4
// body with NO serial tail: 4 independent gathers always in flight; invalid
// slots clamp to the last edge and are zero-selected (masks are wave-uniform
// -> scalar predication, no divergence, no extra latency-serial iterations).
// ---------------------------------------------------------------------------

__global__ __launch_bounds__(256) void agg64_kernel(
    const __half* __restrict__ h, const int* __restrict__ offs,
    const int* __restrict__ offe, const int* __restrict__ esrc,
    const float* __restrict__ dinv, __half* __restrict__ out, int n) {
  int gi = blockIdx.x * 4 + (threadIdx.x >> 6);
  if (gi >= n) return;
  const int lane = threadIdx.x & 63;
  const float di = dinv[gi];

  float a0 = 0.f, a1 = 0.f, a2 = 0.f, a3 = 0.f;
  int e = offs[gi];
  const int e1 = offe[gi];
  const int m = e1 - 1;
  for (; e < e1; e += 4) {
    int s0 = esrc[e];
    int s1 = esrc[min(e + 1, m)];
    int s2 = esrc[min(e + 2, m)];
    int s3 = esrc[min(e + 3, m)];
    float h0 = __half2float(h[((size_t)s0 << 6) + lane]);
    float h1 = __half2float(h[((size_t)s1 << 6) + lane]);
    float h2 = __half2float(h[((size_t)s2 << 6) + lane]);
    float h3 = __half2float(h[((size_t)s3 << 6) + lane]);
    if (e + 1 >= e1) h1 = 0.f;
    if (e + 2 >= e1) h2 = 0.f;
    if (e + 3 >= e1) h3 = 0.f;
    a0 += h0; a1 += h1; a2 += h2; a3 += h3;
  }
  float a = (a0 + a1) + (a2 + a3);
  a += __half2float(h[((size_t)gi << 6) + lane]);   // self (pre-scaled row)
  out[((size_t)gi << 6) + lane] = __float2half_rn(di * a);
}

__global__ __launch_bounds__(256) void agg128_bn_kernel(
    const __half* __restrict__ h, const int* __restrict__ offs,
    const int* __restrict__ offe, const int* __restrict__ esrc,
    const float* __restrict__ dinv,
    const float* __restrict__ bias, const float* __restrict__ gam,
    const float* __restrict__ bet, const float* __restrict__ mean,
    const float* __restrict__ var, __half* __restrict__ out, int n) {
  int gi = blockIdx.x * 4 + (threadIdx.x >> 6);
  if (gi >= n) return;
  const int lane = threadIdx.x & 63;
  const int c = lane << 1;
  const __half2* hp = (const __half2*)h;
  const float di = dinv[gi];

  float ax = 0.f, ay = 0.f, bx = 0.f, by = 0.f;
  float cx = 0.f, cy = 0.f, dx = 0.f, dy = 0.f;
  int e = offs[gi];
  const int e1 = offe[gi];
  const int m = e1 - 1;
  for (; e < e1; e += 4) {
    int s0 = esrc[e];
    int s1 = esrc[min(e + 1, m)];
    int s2 = esrc[min(e + 2, m)];
    int s3 = esrc[min(e + 3, m)];
    float2 h0 = __half22float2(hp[((size_t)s0 << 6) + lane]);
    float2 h1 = __half22float2(hp[((size_t)s1 << 6) + lane]);
    float2 h2 = __half22float2(hp[((size_t)s2 << 6) + lane]);
    float2 h3 = __half22float2(hp[((size_t)s3 << 6) + lane]);
    if (e + 1 >= e1) { h1.x = 0.f; h1.y = 0.f; }
    if (e + 2 >= e1) { h2.x = 0.f; h2.y = 0.f; }
    if (e + 3 >= e1) { h3.x = 0.f; h3.y = 0.f; }
    ax += h0.x; ay += h0.y; bx += h1.x; by += h1.y;
    cx += h2.x; cy += h2.y; dx += h3.x; dy += h3.y;
  }
  ax = (ax + bx) + (cx + dx);
  ay = (ay + by) + (cy + dy);
  float2 hs = __half22float2(hp[((size_t)gi << 6) + lane]);  // self (pre-scaled)
  ax = di * (ax + hs.x);
  ay = di * (ay + hs.y);

  float2 bv = *(const float2*)(bias + c);
  float2 gv = *(const float2*)(gam + c);
  float2 bev = *(const float2*)(bet + c);
  float2 mv = *(const float2*)(mean + c);
  float2 vv = *(const float2*)(var + c);
  float s0 = gv.x * rsqrtf(vv.x + BN_EPS);
  float s1 = gv.y * rsqrtf(vv.y + BN_EPS);
  float o0 = fmaxf(fmaf(ax + bv.x - mv.x, s0, bev.x), 0.f);
  float o1 = fmaxf(fmaf(ay + bv.y - mv.y, s1, bev.y), 0.f);
  ((__half2*)out)[((size_t)gi << 6) + lane] = __floats2half2_rn(o0, o1);
}

// ---------------------------------------------------------------------------

static inline size_t alignup(size_t x, size_t a) { return (x + a - 1) & ~(a - 1); }

extern "C" void kernel_launch(void* const* d_in, const int* in_sizes, int n_in,
                              void* d_out, int out_size, void* d_ws, size_t ws_size,
                              hipStream_t stream) {
  const float* x   = (const float*)d_in[0];
  const int*   src = (const int*)d_in[1];
  const int*   dst = (const int*)d_in[2];
  const float* W0  = (const float*)d_in[3];
  const float* b0  = (const float*)d_in[4];
  const float* g0  = (const float*)d_in[5];
  const float* be0 = (const float*)d_in[6];
  const float* m0  = (const float*)d_in[7];
  const float* v0  = (const float*)d_in[8];
  const float* W1  = (const float*)d_in[9];
  const float* b1  = (const float*)d_in[10];
  const float* g1  = (const float*)d_in[11];
  const float* be1 = (const float*)d_in[12];
  const float* m1  = (const float*)d_in[13];
  const float* v1  = (const float*)d_in[14];
  const float* W2  = (const float*)d_in[15];
  const float* b2  = (const float*)d_in[16];
  const float* g2  = (const float*)d_in[17];
  const float* be2 = (const float*)d_in[18];
  const float* m2  = (const float*)d_in[19];
  const float* v2  = (const float*)d_in[20];
  const float* Wm1 = (const float*)d_in[21];
  const float* bm1 = (const float*)d_in[22];
  const float* Wm2 = (const float*)d_in[23];
  const float* bm2 = (const float*)d_in[24];

  const int N = in_sizes[0] / 64;
  const int E = in_sizes[1];

  char* p = (char*)d_ws;
  auto take = [&](size_t bytes) {
    char* r = p;
    p += alignup(bytes, 256);
    return r;
  };
  const int nbk = (N + BK - 1) / BK;    // buckets (98 for N=50000)
  int*    bcursor= (int*)take(NBMAX * 4);
  int*    offs   = (int*)take((size_t)N * 4);
  int*    offe   = (int*)take((size_t)N * 4);
  float*  dinv   = (float*)take((size_t)N * 4);
  int*    esrc   = (int*)take((size_t)nbk * BCAP * 4);
  int2*   tmp    = (int2*)take((size_t)nbk * BCAP * 8);
  __half* x16    = (__half*)take((size_t)N * 64 * 2);
  __half* aggx16 = (__half*)take((size_t)N * 64 * 2);
  __half* t0     = (__half*)take((size_t)N * 128 * 2);
  __half* t1     = (__half*)take((size_t)N * 128 * 2);
  float*  yout   = (float*)d_out;

  const int TB = 256;
  const int sb = (E + ECH - 1) / ECH;   // scatter blocks
  const int n4 = N * 16;                // float4 count of x
  const int cb = (n4 + 255) / 256;      // cvt blocks

  // --- CSR build (fixed-stride buckets) + fp16 x, 3 dispatches total ---
  hipMemsetAsync(bcursor, 0, NBMAX * 4, stream);
  scatter_cvt_kernel<<<sb + cb, TB, 0, stream>>>(src, dst, bcursor, tmp,
                                                 x, x16, E, nbk, sb, n4);
  bucket_finalize_kernel<<<nbk, TB, 0, stream>>>(tmp, bcursor, offs, offe,
                                                 dinv, esrc, x16, N);

  const int gemmGrid = (N + 127) / 128;
  const int aggGrid = (N + 3) / 4;

  // --- layer 0 (x16 rows pre-scaled by dinv in finalize; agg is pure sum) ---
  agg64_kernel<<<aggGrid, TB, 0, stream>>>(x16, offs, offe, esrc, dinv, aggx16, N);
  mgemm_kernel<64, 128, 3, true><<<gemmGrid, TB, 0, stream>>>(
      aggx16, W0, b0, g0, be0, m0, v0, t0, N);
  // --- layer 1 (GEMM pre-scales rows by dinv via EPI=4; agg sums + BN) ---
  mgemm_kernel<128, 128, 4, true><<<gemmGrid, TB, 0, stream>>>(
      t0, W1, dinv, nullptr, nullptr, nullptr, nullptr, t1, N);
  agg128_bn_kernel<<<aggGrid, TB, 0, stream>>>(t1, offs, offe, esrc, dinv,
                                               b1, g1, be1, m1, v1, t0, N);
  // --- layer 2 ---
  mgemm_kernel<128, 128, 4, true><<<gemmGrid, TB, 0, stream>>>(
      t0, W2, dinv, nullptr, nullptr, nullptr, nullptr, t1, N);
  agg128_bn_kernel<<<aggGrid, TB, 0, stream>>>(t1, offs, offe, esrc, dinv,
                                               b2, g2, be2, m2, v2, t0, N);
  // --- fused MLP ---
  mlp_kernel<<<gemmGrid, TB, 0, stream>>>(t0, Wm1, bm1, Wm2, bm2, yout, N);
}

// Round 6
// 332.093 us; speedup vs baseline: 1.8544x; 1.0138x over previous
//
#include <hip/hip_runtime.h>
#include <hip/hip_fp16.h>

#define BN_EPS 1e-5f
#define BK 512        // dst-nodes per bucket (contiguous node range)
#define NBMAX 128
#define ECH 8192      // edges per scatter block
#define BCAP 9216     // fixed per-bucket capacity (mean 8163, sigma~90 -> 11+ sigma)

typedef _Float16 half_t;
typedef _Float16 half8 __attribute__((ext_vector_type(8)));
typedef float floatx4 __attribute__((ext_vector_type(4)));

// ---------------------------------------------------------------------------
// Preprocess, fixed-stride buckets: bucket b owns tmp/esrc[b*BCAP ..). No
// global histogram or scan passes; per-bucket cursors reserve runs directly.
// CSR is strided (gaps between buckets) -> aggs use explicit offs/offe.
// ---------------------------------------------------------------------------

// blocks [0, sb): scatter {src,dst} into bucket-major tmp (~670B runs/bucket).
// blocks [sb, ..): fp32 -> fp16 copy of x (independent work, merged dispatch).
__global__ __launch_bounds__(256) void scatter_cvt_kernel(
    const int* __restrict__ src, const int* __restrict__ dst,
    int* __restrict__ bcursor, int2* __restrict__ tmp,
    const float* __restrict__ x, __half* __restrict__ x16,
    int E, int nb, int sb, int n4) {
  const int t = threadIdx.x;
  if (blockIdx.x >= sb) {
    int i = (blockIdx.x - sb) * 256 + t;
    if (i < n4) {
      float4 v = *(const float4*)(x + (size_t)i * 4);
      union { __half h[4]; float2 f; } u;
      u.h[0] = __float2half_rn(v.x);
      u.h[1] = __float2half_rn(v.y);
      u.h[2] = __float2half_rn(v.z);
      u.h[3] = __float2half_rn(v.w);
      *(float2*)(x16 + (size_t)i * 4) = u.f;
    }
    return;
  }
  __shared__ int h[NBMAX];
  for (int i = t; i < nb; i += 256) h[i] = 0;
  __syncthreads();
  const int base = blockIdx.x * ECH;
#pragma unroll 8
  for (int p = 0; p < ECH / 256; ++p) {
    int e = base + p * 256 + t;
    if (e < E) atomicAdd(&h[dst[e] >> 9], 1);
  }
  __syncthreads();
  for (int i = t; i < nb; i += 256) {
    int c = h[i];
    h[i] = c ? (i * BCAP + atomicAdd(&bcursor[i], c)) : 0;  // contiguous run
  }
  __syncthreads();
#pragma unroll 8
  for (int p = 0; p < ECH / 256; ++p) {
    int e = base + p * 256 + t;
    if (e < E) {
      int s = src[e], d = dst[e];
      int pos = atomicAdd(&h[d >> 9], 1);
      tmp[pos] = make_int2(s, d);
    }
  }
}

// One block per bucket: LDS degree count -> local scan -> offs/offe/dinv/esrc.
// Also pre-scales this bucket's x16 rows by dinv[row] (dinv-fold for layer 0:
// agg64 then computes out = di * (sum_e x16'[src_e] + x16'[gi]) with no
// per-edge dinv lookup).
__global__ __launch_bounds__(256) void bucket_finalize_kernel(
    const int2* __restrict__ tmp, const int* __restrict__ bcursor,
    int* __restrict__ offs, int* __restrict__ offe, float* __restrict__ dinv,
    int* __restrict__ esrc, __half* __restrict__ x16, int n) {
  __shared__ int deg[BK];
  __shared__ int cur[BK];
  __shared__ float fdi[BK];
  __shared__ int ts[256];
  const int t = threadIdx.x;
  const int b = blockIdx.x;
  const int nbase = b * BK;
  const int nn = min(BK, n - nbase);
  const int cnt = bcursor[b];
  const int2* tp = tmp + (size_t)b * BCAP;
  for (int i = t; i < nn; i += 256) deg[i] = 0;
  __syncthreads();
  for (int e = t; e < cnt; e += 256)
    atomicAdd(&deg[tp[e].y - nbase], 1);
  __syncthreads();
  // exclusive scan of 512 degrees (thread t handles 2t, 2t+1)
  int d0 = (2 * t < nn) ? deg[2 * t] : 0;
  int d1 = (2 * t + 1 < nn) ? deg[2 * t + 1] : 0;
  ts[t] = d0 + d1;
  __syncthreads();
  for (int o = 1; o < 256; o <<= 1) {
    int v = (t >= o) ? ts[t - o] : 0;
    __syncthreads();
    ts[t] += v;
    __syncthreads();
  }
  int base = b * BCAP + ((t == 0) ? 0 : ts[t - 1]);
  if (2 * t < nn) {
    float di = rsqrtf(1.0f + (float)d0);
    offs[nbase + 2 * t] = base;
    offe[nbase + 2 * t] = base + d0;
    cur[2 * t] = base;
    fdi[2 * t] = di;
    dinv[nbase + 2 * t] = di;
  }
  if (2 * t + 1 < nn) {
    float di = rsqrtf(1.0f + (float)d1);
    offs[nbase + 2 * t + 1] = base + d0;
    offe[nbase + 2 * t + 1] = base + d0 + d1;
    cur[2 * t + 1] = base + d0;
    fdi[2 * t + 1] = di;
    dinv[nbase + 2 * t + 1] = di;
  }
  __syncthreads();
  for (int e = t; e < cnt; e += 256) {
    int2 r = tp[e];
    int pos = atomicAdd(&cur[r.y - nbase], 1);
    esrc[pos] = r.x;
  }
  // pre-scale x16 rows of this bucket by dinv[row] (32 half2 per row)
  __half2* xp = (__half2*)x16;
  for (int i = t; i < nn * 32; i += 256) {
    int nl = i >> 5;
    size_t idx = (((size_t)(nbase + nl)) << 5) + (i & 31);
    float2 v = __half22float2(xp[idx]);
    float s = fdi[nl];
    xp[idx] = __floats2half2_rn(v.x * s, v.y * s);
  }
}

// ---------------------------------------------------------------------------
// MFMA fp16 GEMM (fp32 accumulate).  256 thr = 4 waves; 128-row tile.
// Frag layouts (m89/m120): A[m=lane&15][k=quad*8+j]; B[k][n=lane&15];
// C/D row=quad*4+reg, col=lane&15.  LDS stride 72 halfs (2-way = free).
// EPI: 0 none, 1 bias+relu, 2 bias, 3 bias+BN+relu,
//      4 row-scale (bias ptr = per-row dinv; writes dinv[row]*acc).
// ---------------------------------------------------------------------------

template <int FIN, int FOUT, int EPI, bool HALFOUT>
__global__ __launch_bounds__(256) void mgemm_kernel(
    const __half* __restrict__ X, const float* __restrict__ W,
    const float* __restrict__ bias, const float* __restrict__ gam,
    const float* __restrict__ bet, const float* __restrict__ mean,
    const float* __restrict__ var, void* __restrict__ Yv, int n) {
  constexpr int LDK = 72;
  constexpr int NCI = FOUT / 16;
  __shared__ half_t Asm[128 * LDK];
  __shared__ half_t Bsm[FOUT * LDK];

  const int t = threadIdx.x;
  const int wave = t >> 6, lane = t & 63;
  const int quad = lane >> 4, l16 = lane & 15;
  const int rowBase = blockIdx.x * 128;

  floatx4 acc[2][NCI];
#pragma unroll
  for (int i = 0; i < 2; ++i)
#pragma unroll
    for (int ci = 0; ci < NCI; ++ci) acc[i][ci] = (floatx4){0.f, 0.f, 0.f, 0.f};

  for (int kc = 0; kc < FIN; kc += 64) {
    __syncthreads();
    {
      const int kq = t & 15, m0 = t >> 4;
#pragma unroll
      for (int p = 0; p < 8; ++p) {
        int m = p * 16 + m0;
        int row = rowBase + m;
        uint2 v = make_uint2(0u, 0u);
        if (row < n) v = *(const uint2*)(X + (size_t)row * FIN + kc + kq * 4);
        *(uint2*)&Asm[m * LDK + kq * 4] = v;
      }
    }
    {
#pragma unroll
      for (int c0 = 0; c0 < FOUT * 16; c0 += 256) {
        int c = c0 + t;
        int nn = c % FOUT;
        int kg = (c / FOUT) * 4;
        const float* wp = W + (size_t)(kc + kg) * FOUT + nn;
        half_t* d = &Bsm[nn * LDK + kg];
        d[0] = (half_t)wp[0];
        d[1] = (half_t)wp[FOUT];
        d[2] = (half_t)wp[2 * FOUT];
        d[3] = (half_t)wp[3 * FOUT];
      }
    }
    __syncthreads();
#pragma unroll
    for (int kk = 0; kk < 2; ++kk) {
      half8 a0 = *(const half8*)&Asm[(wave * 32 + l16) * LDK + kk * 32 + quad * 8];
      half8 a1 = *(const half8*)&Asm[(wave * 32 + 16 + l16) * LDK + kk * 32 + quad * 8];
#pragma unroll
      for (int ci = 0; ci < NCI; ++ci) {
        half8 b = *(const half8*)&Bsm[(ci * 16 + l16) * LDK + kk * 32 + quad * 8];
        acc[0][ci] = __builtin_amdgcn_mfma_f32_16x16x32_f16(a0, b, acc[0][ci], 0, 0, 0);
        acc[1][ci] = __builtin_amdgcn_mfma_f32_16x16x32_f16(a1, b, acc[1][ci], 0, 0, 0);
      }
    }
  }

  float sc[NCI], sh[NCI];
#pragma unroll
  for (int ci = 0; ci < NCI; ++ci) {
    int col = ci * 16 + l16;
    if constexpr (EPI == 3) {
      float s = gam[col] * rsqrtf(var[col] + BN_EPS);
      sc[ci] = s;
      sh[ci] = (bias[col] - mean[col]) * s + bet[col];
    } else if constexpr (EPI == 1 || EPI == 2) {
      sc[ci] = 1.f;
      sh[ci] = bias[col];
    } else {
      sc[ci] = 1.f;
      sh[ci] = 0.f;
    }
  }
  float rs[2][4];
  if constexpr (EPI == 4) {
#pragma unroll
    for (int ri = 0; ri < 2; ++ri)
#pragma unroll
      for (int r = 0; r < 4; ++r) {
        int row = rowBase + wave * 32 + ri * 16 + quad * 4 + r;
        rs[ri][r] = (row < n) ? bias[row] : 0.f;   // bias ptr = dinv (per-row)
      }
  }
#pragma unroll
  for (int ri = 0; ri < 2; ++ri)
#pragma unroll
    for (int ci = 0; ci < NCI; ++ci) {
      int col = ci * 16 + l16;
#pragma unroll
      for (int r = 0; r < 4; ++r) {
        int row = rowBase + wave * 32 + ri * 16 + quad * 4 + r;
        if (row < n) {
          float v = acc[ri][ci][r];
          if constexpr (EPI == 4) v *= rs[ri][r];
          if constexpr (EPI == 1 || EPI == 2 || EPI == 3) v = fmaf(v, sc[ci], sh[ci]);
          if constexpr (EPI == 1 || EPI == 3) v = fmaxf(v, 0.f);
          if constexpr (HALFOUT)
            ((half_t*)Yv)[(size_t)row * FOUT + col] = (half_t)v;
          else
            ((float*)Yv)[(size_t)row * FOUT + col] = v;
        }
      }
    }
}

// ---------------------------------------------------------------------------
// Fused MLP: Y = relu(X@W1+b1)@W2 + b2.  H kept in LDS (fp16, stride 136).
// ---------------------------------------------------------------------------

__global__ __launch_bounds__(256) void mlp_kernel(
    const __half* __restrict__ X, const float* __restrict__ W1,
    const float* __restrict__ b1f, const float* __restrict__ W2,
    const float* __restrict__ b2f, float* __restrict__ Y, int n) {
  constexpr int LDK = 72;
  constexpr int LDK2 = 136;
  __shared__ half_t smem[(128 + 64) * LDK2];
  half_t* As1 = smem;
  half_t* Bs1 = smem + 128 * LDK;
  half_t* As2 = smem;
  half_t* Bs2 = smem + 128 * LDK2;

  const int t = threadIdx.x;
  const int wave = t >> 6, lane = t & 63;
  const int quad = lane >> 4, l16 = lane & 15;
  const int rowBase = blockIdx.x * 128;

  floatx4 acc[2][8];
#pragma unroll
  for (int i = 0; i < 2; ++i)
#pragma unroll
    for (int ci = 0; ci < 8; ++ci) acc[i][ci] = (floatx4){0.f, 0.f, 0.f, 0.f};

  for (int kc = 0; kc < 128; kc += 64) {
    __syncthreads();
    {
      const int kq = t & 15, m0 = t >> 4;
#pragma unroll
      for (int p = 0; p < 8; ++p) {
        int m = p * 16 + m0;
        int row = rowBase + m;
        uint2 v = make_uint2(0u, 0u);
        if (row < n) v = *(const uint2*)(X + (size_t)row * 128 + kc + kq * 4);
        *(uint2*)&As1[m * LDK + kq * 4] = v;
      }
    }
    {
#pragma unroll
      for (int c0 = 0; c0 < 128 * 16; c0 += 256) {
        int c = c0 + t;
        int nn = c & 127;
        int kg = (c >> 7) << 2;
        const float* wp = W1 + (size_t)(kc + kg) * 128 + nn;
        half_t* d = &Bs1[nn * LDK + kg];
        d[0] = (half_t)wp[0];
        d[1] = (half_t)wp[128];
        d[2] = (half_t)wp[256];
        d[3] = (half_t)wp[384];
      }
    }
    __syncthreads();
#pragma unroll
    for (int kk = 0; kk < 2; ++kk) {
      half8 a0 = *(const half8*)&As1[(wave * 32 + l16) * LDK + kk * 32 + quad * 8];
      half8 a1 = *(const half8*)&As1[(wave * 32 + 16 + l16) * LDK + kk * 32 + quad * 8];
#pragma unroll
      for (int ci = 0; ci < 8; ++ci) {
        half8 b = *(const half8*)&Bs1[(ci * 16 + l16) * LDK + kk * 32 + quad * 8];
        acc[0][ci] = __builtin_amdgcn_mfma_f32_16x16x32_f16(a0, b, acc[0][ci], 0, 0, 0);
        acc[1][ci] = __builtin_amdgcn_mfma_f32_16x16x32_f16(a1, b, acc[1][ci], 0, 0, 0);
      }
    }
  }
  __syncthreads();

#pragma unroll
  for (int ri = 0; ri < 2; ++ri)
#pragma unroll
    for (int ci = 0; ci < 8; ++ci) {
      int col = ci * 16 + l16;
      float bz = b1f[col];
#pragma unroll
      for (int r = 0; r < 4; ++r) {
        int m = wave * 32 + ri * 16 + quad * 4 + r;
        As2[m * LDK2 + col] = (half_t)fmaxf(acc[ri][ci][r] + bz, 0.f);
      }
    }
  {
#pragma unroll
    for (int c0 = 0; c0 < 64 * 32; c0 += 256) {
      int c = c0 + t;
      int nn = c & 63;
      int kg = (c >> 6) << 2;
      const float* wp = W2 + (size_t)kg * 64 + nn;
      half_t* d = &Bs2[nn * LDK2 + kg];
      d[0] = (half_t)wp[0];
      d[1] = (half_t)wp[64];
      d[2] = (half_t)wp[128];
      d[3] = (half_t)wp[192];
    }
  }
  __syncthreads();

  floatx4 acc2[2][4];
#pragma unroll
  for (int i = 0; i < 2; ++i)
#pragma unroll
    for (int ci = 0; ci < 4; ++ci) acc2[i][ci] = (floatx4){0.f, 0.f, 0.f, 0.f};
#pragma unroll
  for (int kk = 0; kk < 4; ++kk) {
    half8 a0 = *(const half8*)&As2[(wave * 32 + l16) * LDK2 + kk * 32 + quad * 8];
    half8 a1 = *(const half8*)&As2[(wave * 32 + 16 + l16) * LDK2 + kk * 32 + quad * 8];
#pragma unroll
    for (int ci = 0; ci < 4; ++ci) {
      half8 b = *(const half8*)&Bs2[(ci * 16 + l16) * LDK2 + kk * 32 + quad * 8];
      acc2[0][ci] = __builtin_amdgcn_mfma_f32_16x16x32_f16(a0, b, acc2[0][ci], 0, 0, 0);
      acc2[1][ci] = __builtin_amdgcn_mfma_f32_16x16x32_f16(a1, b, acc2[1][ci], 0, 0, 0);
    }
  }
#pragma unroll
  for (int ri = 0; ri < 2; ++ri)
#pragma unroll
    for (int ci = 0; ci < 4; ++ci) {
      int col = ci * 16 + l16;
      float bz = b2f[col];
#pragma unroll
      for (int r = 0; r < 4; ++r) {
        int row = rowBase + wave * 32 + ri * 16 + quad * 4 + r;
        if (row < n) Y[(size_t)row * 64 + col] = acc2[ri][ci][r] + bz;
      }
    }
}

// ---------------------------------------------------------------------------
// Aggregations: one wave per node, PACKED gathers — multiple rows per load
// instruction (fewer, fatter vmem requests; round-4 showed request count is
// a co-limiting resource alongside the per-CU miss queue).
// agg128: 2 rows/instr (half-wave per edge, 8B/lane), 4 edges per iter via
// 2 loads.  agg64: 4 rows/instr (16 lanes per edge), 8 edges per iter.
// Per-lane clamp+zero masks -> no serial tail.  Pure sums (dinv folded
// upstream); cross-group shfl_xor reduce; leader lanes add self row, apply
// scale/BN, store the full row.
// ---------------------------------------------------------------------------

__global__ __launch_bounds__(256) void agg64_kernel(
    const __half* __restrict__ h, const int* __restrict__ offs,
    const int* __restrict__ offe, const int* __restrict__ esrc,
    const float* __restrict__ dinv, __half* __restrict__ out, int n) {
  int gi = blockIdx.x * 4 + (threadIdx.x >> 6);
  if (gi >= n) return;
  const int lane = threadIdx.x & 63;
  const int q = lane >> 4;            // edge slot 0..3
  const int j = lane & 15;            // feats 4j..4j+3
  const __half2* hp = (const __half2*)h;
  const float di = dinv[gi];

  float ax = 0.f, ay = 0.f, az = 0.f, aw = 0.f;
  float bx = 0.f, by = 0.f, bz = 0.f, bw = 0.f;
  int e = offs[gi];
  const int e1 = offe[gi];
  const int m = e1 - 1;
  for (; e < e1; e += 8) {
    int i0 = e + q;                   // edges e..e+3 across the 4 groups
    int i1 = e + 4 + q;               // edges e+4..e+7
    int s0 = esrc[min(i0, m)];
    int s1 = esrc[min(i1, m)];
    uint2 r0 = *(const uint2*)(hp + (((size_t)s0) << 5) + j * 2);
    uint2 r1 = *(const uint2*)(hp + (((size_t)s1) << 5) + j * 2);
    if (i0 >= e1) { r0.x = 0u; r0.y = 0u; }
    if (i1 >= e1) { r1.x = 0u; r1.y = 0u; }
    float2 p0 = __half22float2(*(__half2*)&r0.x);
    float2 p1 = __half22float2(*(__half2*)&r0.y);
    float2 q0 = __half22float2(*(__half2*)&r1.x);
    float2 q1 = __half22float2(*(__half2*)&r1.y);
    ax += p0.x; ay += p0.y; az += p1.x; aw += p1.y;
    bx += q0.x; by += q0.y; bz += q1.x; bw += q1.y;
  }
  ax += bx; ay += by; az += bz; aw += bw;
  // combine the 4 edge groups (lanes j, j+16, j+32, j+48 hold same feats)
  ax += __shfl_xor(ax, 16); ay += __shfl_xor(ay, 16);
  az += __shfl_xor(az, 16); aw += __shfl_xor(aw, 16);
  ax += __shfl_xor(ax, 32); ay += __shfl_xor(ay, 32);
  az += __shfl_xor(az, 32); aw += __shfl_xor(aw, 32);
  if (q == 0) {
    uint2 rs = *(const uint2*)(hp + (((size_t)gi) << 5) + j * 2);  // self (scaled)
    float2 s0 = __half22float2(*(__half2*)&rs.x);
    float2 s1 = __half22float2(*(__half2*)&rs.y);
    __half2 h0 = __floats2half2_rn(di * (ax + s0.x), di * (ay + s0.y));
    __half2 h1 = __floats2half2_rn(di * (az + s1.x), di * (aw + s1.y));
    uint2 ov;
    ov.x = *(unsigned*)&h0;
    ov.y = *(unsigned*)&h1;
    *(uint2*)((__half2*)out + (((size_t)gi) << 5) + j * 2) = ov;
  }
}

__global__ __launch_bounds__(256) void agg128_bn_kernel(
    const __half* __restrict__ h, const int* __restrict__ offs,
    const int* __restrict__ offe, const int* __restrict__ esrc,
    const float* __restrict__ dinv,
    const float* __restrict__ bias, const float* __restrict__ gam,
    const float* __restrict__ bet, const float* __restrict__ mean,
    const float* __restrict__ var, __half* __restrict__ out, int n) {
  int gi = blockIdx.x * 4 + (threadIdx.x >> 6);
  if (gi >= n) return;
  const int lane = threadIdx.x & 63;
  const int hh = lane >> 5;           // half-wave: edge parity
  const int j = lane & 31;            // feats 4j..4j+3
  const __half2* hp = (const __half2*)h;
  const float di = dinv[gi];

  float ax = 0.f, ay = 0.f, az = 0.f, aw = 0.f;
  float bx = 0.f, by = 0.f, bz = 0.f, bw = 0.f;
  int e = offs[gi];
  const int e1 = offe[gi];
  const int m = e1 - 1;
  for (; e < e1; e += 4) {
    int i0 = e + hh;                  // edges e, e+1 across half-waves
    int i1 = e + 2 + hh;              // edges e+2, e+3
    int s0 = esrc[min(i0, m)];
    int s1 = esrc[min(i1, m)];
    uint2 r0 = *(const uint2*)(hp + (((size_t)s0) << 6) + j * 2);
    uint2 r1 = *(const uint2*)(hp + (((size_t)s1) << 6) + j * 2);
    if (i0 >= e1) { r0.x = 0u; r0.y = 0u; }
    if (i1 >= e1) { r1.x = 0u; r1.y = 0u; }
    float2 p0 = __half22float2(*(__half2*)&r0.x);
    float2 p1 = __half22float2(*(__half2*)&r0.y);
    float2 q0 = __half22float2(*(__half2*)&r1.x);
    float2 q1 = __half22float2(*(__half2*)&r1.y);
    ax += p0.x; ay += p0.y; az += p1.x; aw += p1.y;
    bx += q0.x; by += q0.y; bz += q1.x; bw += q1.y;
  }
  ax += bx; ay += by; az += bz; aw += bw;
  // combine half-waves (lanes j and j+32 hold same feats, different edges)
  ax += __shfl_xor(ax, 32); ay += __shfl_xor(ay, 32);
  az += __shfl_xor(az, 32); aw += __shfl_xor(aw, 32);
  if (hh == 0) {
    uint2 rs = *(const uint2*)(hp + (((size_t)gi) << 6) + j * 2);  // self (scaled)
    float2 s0 = __half22float2(*(__half2*)&rs.x);
    float2 s1 = __half22float2(*(__half2*)&rs.y);
    float v0 = di * (ax + s0.x);
    float v1 = di * (ay + s0.y);
    float v2 = di * (az + s1.x);
    float v3 = di * (aw + s1.y);
    const int c = j * 4;
    float4 bv = *(const float4*)(bias + c);
    float4 gv = *(const float4*)(gam + c);
    float4 bev = *(const float4*)(bet + c);
    float4 mv = *(const float4*)(mean + c);
    float4 vv = *(const float4*)(var + c);
    float o0 = fmaxf(fmaf(v0 + bv.x - mv.x, gv.x * rsqrtf(vv.x + BN_EPS), bev.x), 0.f);
    float o1 = fmaxf(fmaf(v1 + bv.y - mv.y, gv.y * rsqrtf(vv.y + BN_EPS), bev.y), 0.f);
    float o2 = fmaxf(fmaf(v2 + bv.z - mv.z, gv.z * rsqrtf(vv.z + BN_EPS), bev.z), 0.f);
    float o3 = fmaxf(fmaf(v3 + bv.w - mv.w, gv.w * rsqrtf(vv.w + BN_EPS), bev.w), 0.f);
    __half2 h0 = __floats2half2_rn(o0, o1);
    __half2 h1 = __floats2half2_rn(o2, o3);
    uint2 ov;
    ov.x = *(unsigned*)&h0;
    ov.y = *(unsigned*)&h1;
    *(uint2*)((__half2*)out + (((size_t)gi) << 6) + j * 2) = ov;
  }
}

// ---------------------------------------------------------------------------

static inline size_t alignup(size_t x, size_t a) { return (x + a - 1) & ~(a - 1); }

extern "C" void kernel_launch(void* const* d_in, const int* in_sizes, int n_in,
                              void* d_out, int out_size, void* d_ws, size_t ws_size,
                              hipStream_t stream) {
  const float* x   = (const float*)d_in[0];
  const int*   src = (const int*)d_in[1];
  const int*   dst = (const int*)d_in[2];
  const float* W0  = (const float*)d_in[3];
  const float* b0  = (const float*)d_in[4];
  const float* g0  = (const float*)d_in[5];
  const float* be0 = (const float*)d_in[6];
  const float* m0  = (const float*)d_in[7];
  const float* v0  = (const float*)d_in[8];
  const float* W1  = (const float*)d_in[9];
  const float* b1  = (const float*)d_in[10];
  const float* g1  = (const float*)d_in[11];
  const float* be1 = (const float*)d_in[12];
  const float* m1  = (const float*)d_in[13];
  const float* v1  = (const float*)d_in[14];
  const float* W2  = (const float*)d_in[15];
  const float* b2  = (const float*)d_in[16];
  const float* g2  = (const float*)d_in[17];
  const float* be2 = (const float*)d_in[18];
  const float* m2  = (const float*)d_in[19];
  const float* v2  = (const float*)d_in[20];
  const float* Wm1 = (const float*)d_in[21];
  const float* bm1 = (const float*)d_in[22];
  const float* Wm2 = (const float*)d_in[23];
  const float* bm2 = (const float*)d_in[24];

  const int N = in_sizes[0] / 64;
  const int E = in_sizes[1];

  char* p = (char*)d_ws;
  auto take = [&](size_t bytes) {
    char* r = p;
    p += alignup(bytes, 256);
    return r;
  };
  const int nbk = (N + BK - 1) / BK;    // buckets (98 for N=50000)
  int*    bcursor= (int*)take(NBMAX * 4);
  int*    offs   = (int*)take((size_t)N * 4);
  int*    offe   = (int*)take((size_t)N * 4);
  float*  dinv   = (float*)take((size_t)N * 4);
  int*    esrc   = (int*)take((size_t)nbk * BCAP * 4);
  int2*   tmp    = (int2*)take((size_t)nbk * BCAP * 8);
  __half* x16    = (__half*)take((size_t)N * 64 * 2);
  __half* aggx16 = (__half*)take((size_t)N * 64 * 2);
  __half* t0     = (__half*)take((size_t)N * 128 * 2);
  __half* t1     = (__half*)take((size_t)N * 128 * 2);
  float*  yout   = (float*)d_out;

  const int TB = 256;
  const int sb = (E + ECH - 1) / ECH;   // scatter blocks
  const int n4 = N * 16;                // float4 count of x
  const int cb = (n4 + 255) / 256;      // cvt blocks

  // --- CSR build (fixed-stride buckets) + fp16 x, 3 dispatches total ---
  hipMemsetAsync(bcursor, 0, NBMAX * 4, stream);
  scatter_cvt_kernel<<<sb + cb, TB, 0, stream>>>(src, dst, bcursor, tmp,
                                                 x, x16, E, nbk, sb, n4);
  bucket_finalize_kernel<<<nbk, TB, 0, stream>>>(tmp, bcursor, offs, offe,
                                                 dinv, esrc, x16, N);

  const int gemmGrid = (N + 127) / 128;
  const int aggGrid = (N + 3) / 4;

  // --- layer 0 (x16 rows pre-scaled by dinv in finalize; agg is pure sum) ---
  agg64_kernel<<<aggGrid, TB, 0, stream>>>(x16, offs, offe, esrc, dinv, aggx16, N);
  mgemm_kernel<64, 128, 3, true><<<gemmGrid, TB, 0, stream>>>(
      aggx16, W0, b0, g0, be0, m0, v0, t0, N);
  // --- layer 1 (GEMM pre-scales rows by dinv via EPI=4; agg sums + BN) ---
  mgemm_kernel<128, 128, 4, true><<<gemmGrid, TB, 0, stream>>>(
      t0, W1, dinv, nullptr, nullptr, nullptr, nullptr, t1, N);
  agg128_bn_kernel<<<aggGrid, TB, 0, stream>>>(t1, offs, offe, esrc, dinv,
                                               b1, g1, be1, m1, v1, t0, N);
  // --- layer 2 ---
  mgemm_kernel<128, 128, 4, true><<<gemmGrid, TB, 0, stream>>>(
      t0, W2, dinv, nullptr, nullptr, nullptr, nullptr, t1, N);
  agg128_bn_kernel<<<aggGrid, TB, 0, stream>>>(t1, offs, offe, esrc, dinv,
                                               b2, g2, be2, m2, v2, t0, N);
  // --- fused MLP ---
  mlp_kernel<<<gemmGrid, TB, 0, stream>>>(t0, Wm1, bm1, Wm2, bm2, yout, N);
}

// Round 7
// 315.294 us; speedup vs baseline: 1.9532x; 1.0533x over previous
//
#include <hip/hip_runtime.h>
#include <hip/hip_fp16.h>

#define BN_EPS 1e-5f
#define BK 512        // dst-nodes per bucket (contiguous node range)
#define NBMAX 128
#define ECH 8192      // edges per scatter block
#define BCAP 9216     // fixed per-bucket capacity (mean 8163, sigma~90 -> 11+ sigma)
#define ECAP 64       // staged edge-index capacity per node (Poisson(16): P(>64)~1e-20)

typedef _Float16 half_t;
typedef _Float16 half8 __attribute__((ext_vector_type(8)));
typedef float floatx4 __attribute__((ext_vector_type(4)));

// ---------------------------------------------------------------------------
// Preprocess, fixed-stride buckets: bucket b owns tmp/esrc[b*BCAP ..). No
// global histogram or scan passes; per-bucket cursors reserve runs directly.
// CSR is strided (gaps between buckets) -> aggs use explicit offs/offe.
// ---------------------------------------------------------------------------

// blocks [0, sb): scatter {src,dst} into bucket-major tmp (~670B runs/bucket).
// blocks [sb, ..): fp32 -> fp16 copy of x (independent work, merged dispatch).
__global__ __launch_bounds__(256) void scatter_cvt_kernel(
    const int* __restrict__ src, const int* __restrict__ dst,
    int* __restrict__ bcursor, int2* __restrict__ tmp,
    const float* __restrict__ x, __half* __restrict__ x16,
    int E, int nb, int sb, int n4) {
  const int t = threadIdx.x;
  if (blockIdx.x >= sb) {
    int i = (blockIdx.x - sb) * 256 + t;
    if (i < n4) {
      float4 v = *(const float4*)(x + (size_t)i * 4);
      union { __half h[4]; float2 f; } u;
      u.h[0] = __float2half_rn(v.x);
      u.h[1] = __float2half_rn(v.y);
      u.h[2] = __float2half_rn(v.z);
      u.h[3] = __float2half_rn(v.w);
      *(float2*)(x16 + (size_t)i * 4) = u.f;
    }
    return;
  }
  __shared__ int h[NBMAX];
  for (int i = t; i < nb; i += 256) h[i] = 0;
  __syncthreads();
  const int base = blockIdx.x * ECH;
#pragma unroll 8
  for (int p = 0; p < ECH / 256; ++p) {
    int e = base + p * 256 + t;
    if (e < E) atomicAdd(&h[dst[e] >> 9], 1);
  }
  __syncthreads();
  for (int i = t; i < nb; i += 256) {
    int c = h[i];
    h[i] = c ? (i * BCAP + atomicAdd(&bcursor[i], c)) : 0;  // contiguous run
  }
  __syncthreads();
#pragma unroll 8
  for (int p = 0; p < ECH / 256; ++p) {
    int e = base + p * 256 + t;
    if (e < E) {
      int s = src[e], d = dst[e];
      int pos = atomicAdd(&h[d >> 9], 1);
      tmp[pos] = make_int2(s, d);
    }
  }
}

// One block per bucket: LDS degree count -> local scan -> offs/offe/dinv/esrc.
// Also pre-scales this bucket's x16 rows by dinv[row] (dinv-fold for layer 0:
// agg64 then computes out = di * (sum_e x16'[src_e] + x16'[gi]) with no
// per-edge dinv lookup).
__global__ __launch_bounds__(256) void bucket_finalize_kernel(
    const int2* __restrict__ tmp, const int* __restrict__ bcursor,
    int* __restrict__ offs, int* __restrict__ offe, float* __restrict__ dinv,
    int* __restrict__ esrc, __half* __restrict__ x16, int n) {
  __shared__ int deg[BK];
  __shared__ int cur[BK];
  __shared__ float fdi[BK];
  __shared__ int ts[256];
  const int t = threadIdx.x;
  const int b = blockIdx.x;
  const int nbase = b * BK;
  const int nn = min(BK, n - nbase);
  const int cnt = bcursor[b];
  const int2* tp = tmp + (size_t)b * BCAP;
  for (int i = t; i < nn; i += 256) deg[i] = 0;
  __syncthreads();
  for (int e = t; e < cnt; e += 256)
    atomicAdd(&deg[tp[e].y - nbase], 1);
  __syncthreads();
  // exclusive scan of 512 degrees (thread t handles 2t, 2t+1)
  int d0 = (2 * t < nn) ? deg[2 * t] : 0;
  int d1 = (2 * t + 1 < nn) ? deg[2 * t + 1] : 0;
  ts[t] = d0 + d1;
  __syncthreads();
  for (int o = 1; o < 256; o <<= 1) {
    int v = (t >= o) ? ts[t - o] : 0;
    __syncthreads();
    ts[t] += v;
    __syncthreads();
  }
  int base = b * BCAP + ((t == 0) ? 0 : ts[t - 1]);
  if (2 * t < nn) {
    float di = rsqrtf(1.0f + (float)d0);
    offs[nbase + 2 * t] = base;
    offe[nbase + 2 * t] = base + d0;
    cur[2 * t] = base;
    fdi[2 * t] = di;
    dinv[nbase + 2 * t] = di;
  }
  if (2 * t + 1 < nn) {
    float di = rsqrtf(1.0f + (float)d1);
    offs[nbase + 2 * t + 1] = base + d0;
    offe[nbase + 2 * t + 1] = base + d0 + d1;
    cur[2 * t + 1] = base + d0;
    fdi[2 * t + 1] = di;
    dinv[nbase + 2 * t + 1] = di;
  }
  __syncthreads();
  for (int e = t; e < cnt; e += 256) {
    int2 r = tp[e];
    int pos = atomicAdd(&cur[r.y - nbase], 1);
    esrc[pos] = r.x;
  }
  // pre-scale x16 rows of this bucket by dinv[row] (32 half2 per row)
  __half2* xp = (__half2*)x16;
  for (int i = t; i < nn * 32; i += 256) {
    int nl = i >> 5;
    size_t idx = (((size_t)(nbase + nl)) << 5) + (i & 31);
    float2 v = __half22float2(xp[idx]);
    float s = fdi[nl];
    xp[idx] = __floats2half2_rn(v.x * s, v.y * s);
  }
}

// ---------------------------------------------------------------------------
// MFMA fp16 GEMM (fp32 accumulate).  256 thr = 4 waves; 128-row tile.
// Frag layouts (m89/m120): A[m=lane&15][k=quad*8+j]; B[k][n=lane&15];
// C/D row=quad*4+reg, col=lane&15.  LDS stride 72 halfs (2-way = free).
// EPI: 0 none, 1 bias+relu, 2 bias, 3 bias+BN+relu,
//      4 row-scale (bias ptr = per-row dinv; writes dinv[row]*acc).
// ---------------------------------------------------------------------------

template <int FIN, int FOUT, int EPI, bool HALFOUT>
__global__ __launch_bounds__(256) void mgemm_kernel(
    const __half* __restrict__ X, const float* __restrict__ W,
    const float* __restrict__ bias, const float* __restrict__ gam,
    const float* __restrict__ bet, const float* __restrict__ mean,
    const float* __restrict__ var, void* __restrict__ Yv, int n) {
  constexpr int LDK = 72;
  constexpr int NCI = FOUT / 16;
  __shared__ half_t Asm[128 * LDK];
  __shared__ half_t Bsm[FOUT * LDK];

  const int t = threadIdx.x;
  const int wave = t >> 6, lane = t & 63;
  const int quad = lane >> 4, l16 = lane & 15;
  const int rowBase = blockIdx.x * 128;

  floatx4 acc[2][NCI];
#pragma unroll
  for (int i = 0; i < 2; ++i)
#pragma unroll
    for (int ci = 0; ci < NCI; ++ci) acc[i][ci] = (floatx4){0.f, 0.f, 0.f, 0.f};

  for (int kc = 0; kc < FIN; kc += 64) {
    __syncthreads();
    {
      const int kq = t & 15, m0 = t >> 4;
#pragma unroll
      for (int p = 0; p < 8; ++p) {
        int m = p * 16 + m0;
        int row = rowBase + m;
        uint2 v = make_uint2(0u, 0u);
        if (row < n) v = *(const uint2*)(X + (size_t)row * FIN + kc + kq * 4);
        *(uint2*)&Asm[m * LDK + kq * 4] = v;
      }
    }
    {
#pragma unroll
      for (int c0 = 0; c0 < FOUT * 16; c0 += 256) {
        int c = c0 + t;
        int nn = c % FOUT;
        int kg = (c / FOUT) * 4;
        const float* wp = W + (size_t)(kc + kg) * FOUT + nn;
        half_t* d = &Bsm[nn * LDK + kg];
        d[0] = (half_t)wp[0];
        d[1] = (half_t)wp[FOUT];
        d[2] = (half_t)wp[2 * FOUT];
        d[3] = (half_t)wp[3 * FOUT];
      }
    }
    __syncthreads();
#pragma unroll
    for (int kk = 0; kk < 2; ++kk) {
      half8 a0 = *(const half8*)&Asm[(wave * 32 + l16) * LDK + kk * 32 + quad * 8];
      half8 a1 = *(const half8*)&Asm[(wave * 32 + 16 + l16) * LDK + kk * 32 + quad * 8];
#pragma unroll
      for (int ci = 0; ci < NCI; ++ci) {
        half8 b = *(const half8*)&Bsm[(ci * 16 + l16) * LDK + kk * 32 + quad * 8];
        acc[0][ci] = __builtin_amdgcn_mfma_f32_16x16x32_f16(a0, b, acc[0][ci], 0, 0, 0);
        acc[1][ci] = __builtin_amdgcn_mfma_f32_16x16x32_f16(a1, b, acc[1][ci], 0, 0, 0);
      }
    }
  }

  float sc[NCI], sh[NCI];
#pragma unroll
  for (int ci = 0; ci < NCI; ++ci) {
    int col = ci * 16 + l16;
    if constexpr (EPI == 3) {
      float s = gam[col] * rsqrtf(var[col] + BN_EPS);
      sc[ci] = s;
      sh[ci] = (bias[col] - mean[col]) * s + bet[col];
    } else if constexpr (EPI == 1 || EPI == 2) {
      sc[ci] = 1.f;
      sh[ci] = bias[col];
    } else {
      sc[ci] = 1.f;
      sh[ci] = 0.f;
    }
  }
  float rs[2][4];
  if constexpr (EPI == 4) {
#pragma unroll
    for (int ri = 0; ri < 2; ++ri)
#pragma unroll
      for (int r = 0; r < 4; ++r) {
        int row = rowBase + wave * 32 + ri * 16 + quad * 4 + r;
        rs[ri][r] = (row < n) ? bias[row] : 0.f;   // bias ptr = dinv (per-row)
      }
  }
#pragma unroll
  for (int ri = 0; ri < 2; ++ri)
#pragma unroll
    for (int ci = 0; ci < NCI; ++ci) {
      int col = ci * 16 + l16;
#pragma unroll
      for (int r = 0; r < 4; ++r) {
        int row = rowBase + wave * 32 + ri * 16 + quad * 4 + r;
        if (row < n) {
          float v = acc[ri][ci][r];
          if constexpr (EPI == 4) v *= rs[ri][r];
          if constexpr (EPI == 1 || EPI == 2 || EPI == 3) v = fmaf(v, sc[ci], sh[ci]);
          if constexpr (EPI == 1 || EPI == 3) v = fmaxf(v, 0.f);
          if constexpr (HALFOUT)
            ((half_t*)Yv)[(size_t)row * FOUT + col] = (half_t)v;
          else
            ((float*)Yv)[(size_t)row * FOUT + col] = v;
        }
      }
    }
}

// ---------------------------------------------------------------------------
// Fused MLP: Y = relu(X@W1+b1)@W2 + b2.  H kept in LDS (fp16, stride 136).
// ---------------------------------------------------------------------------

__global__ __launch_bounds__(256) void mlp_kernel(
    const __half* __restrict__ X, const float* __restrict__ W1,
    const float* __restrict__ b1f, const float* __restrict__ W2,
    const float* __restrict__ b2f, float* __restrict__ Y, int n) {
  constexpr int LDK = 72;
  constexpr int LDK2 = 136;
  __shared__ half_t smem[(128 + 64) * LDK2];
  half_t* As1 = smem;
  half_t* Bs1 = smem + 128 * LDK;
  half_t* As2 = smem;
  half_t* Bs2 = smem + 128 * LDK2;

  const int t = threadIdx.x;
  const int wave = t >> 6, lane = t & 63;
  const int quad = lane >> 4, l16 = lane & 15;
  const int rowBase = blockIdx.x * 128;

  floatx4 acc[2][8];
#pragma unroll
  for (int i = 0; i < 2; ++i)
#pragma unroll
    for (int ci = 0; ci < 8; ++ci) acc[i][ci] = (floatx4){0.f, 0.f, 0.f, 0.f};

  for (int kc = 0; kc < 128; kc += 64) {
    __syncthreads();
    {
      const int kq = t & 15, m0 = t >> 4;
#pragma unroll
      for (int p = 0; p < 8; ++p) {
        int m = p * 16 + m0;
        int row = rowBase + m;
        uint2 v = make_uint2(0u, 0u);
        if (row < n) v = *(const uint2*)(X + (size_t)row * 128 + kc + kq * 4);
        *(uint2*)&As1[m * LDK + kq * 4] = v;
      }
    }
    {
#pragma unroll
      for (int c0 = 0; c0 < 128 * 16; c0 += 256) {
        int c = c0 + t;
        int nn = c & 127;
        int kg = (c >> 7) << 2;
        const float* wp = W1 + (size_t)(kc + kg) * 128 + nn;
        half_t* d = &Bs1[nn * LDK + kg];
        d[0] = (half_t)wp[0];
        d[1] = (half_t)wp[128];
        d[2] = (half_t)wp[256];
        d[3] = (half_t)wp[384];
      }
    }
    __syncthreads();
#pragma unroll
    for (int kk = 0; kk < 2; ++kk) {
      half8 a0 = *(const half8*)&As1[(wave * 32 + l16) * LDK + kk * 32 + quad * 8];
      half8 a1 = *(const half8*)&As1[(wave * 32 + 16 + l16) * LDK + kk * 32 + quad * 8];
#pragma unroll
      for (int ci = 0; ci < 8; ++ci) {
        half8 b = *(const half8*)&Bs1[(ci * 16 + l16) * LDK + kk * 32 + quad * 8];
        acc[0][ci] = __builtin_amdgcn_mfma_f32_16x16x32_f16(a0, b, acc[0][ci], 0, 0, 0);
        acc[1][ci] = __builtin_amdgcn_mfma_f32_16x16x32_f16(a1, b, acc[1][ci], 0, 0, 0);
      }
    }
  }
  __syncthreads();

#pragma unroll
  for (int ri = 0; ri < 2; ++ri)
#pragma unroll
    for (int ci = 0; ci < 8; ++ci) {
      int col = ci * 16 + l16;
      float bz = b1f[col];
#pragma unroll
      for (int r = 0; r < 4; ++r) {
        int m = wave * 32 + ri * 16 + quad * 4 + r;
        As2[m * LDK2 + col] = (half_t)fmaxf(acc[ri][ci][r] + bz, 0.f);
      }
    }
  {
#pragma unroll
    for (int c0 = 0; c0 < 64 * 32; c0 += 256) {
      int c = c0 + t;
      int nn = c & 63;
      int kg = (c >> 6) << 2;
      const float* wp = W2 + (size_t)kg * 64 + nn;
      half_t* d = &Bs2[nn * LDK2 + kg];
      d[0] = (half_t)wp[0];
      d[1] = (half_t)wp[64];
      d[2] = (half_t)wp[128];
      d[3] = (half_t)wp[192];
    }
  }
  __syncthreads();

  floatx4 acc2[2][4];
#pragma unroll
  for (int i = 0; i < 2; ++i)
#pragma unroll
    for (int ci = 0; ci < 4; ++ci) acc2[i][ci] = (floatx4){0.f, 0.f, 0.f, 0.f};
#pragma unroll
  for (int kk = 0; kk < 4; ++kk) {
    half8 a0 = *(const half8*)&As2[(wave * 32 + l16) * LDK2 + kk * 32 + quad * 8];
    half8 a1 = *(const half8*)&As2[(wave * 32 + 16 + l16) * LDK2 + kk * 32 + quad * 8];
#pragma unroll
    for (int ci = 0; ci < 4; ++ci) {
      half8 b = *(const half8*)&Bs2[(ci * 16 + l16) * LDK2 + kk * 32 + quad * 8];
      acc2[0][ci] = __builtin_amdgcn_mfma_f32_16x16x32_f16(a0, b, acc2[0][ci], 0, 0, 0);
      acc2[1][ci] = __builtin_amdgcn_mfma_f32_16x16x32_f16(a1, b, acc2[1][ci], 0, 0, 0);
    }
  }
#pragma unroll
  for (int ri = 0; ri < 2; ++ri)
#pragma unroll
    for (int ci = 0; ci < 4; ++ci) {
      int col = ci * 16 + l16;
      float bz = b2f[col];
#pragma unroll
      for (int r = 0; r < 4; ++r) {
        int row = rowBase + wave * 32 + ri * 16 + quad * 4 + r;
        if (row < n) Y[(size_t)row * 64 + col] = acc2[ri][ci][r] + bz;
      }
    }
}

// ---------------------------------------------------------------------------
// Aggregations with LDS-staged edge indices: one wave per node.  The node's
// edge list (<=ECAP, Poisson(16) tail beyond 64 ~ 0) is staged into LDS with
// ONE coalesced wave-wide load, removing the dependent global esrc load from
// the gather loop.  The loop then issues 4 packed row-loads back-to-back per
// iteration (agg128: 8 edges/16 lines in flight; agg64: 16 edges/16 lines) —
// ~16x the per-wave line concurrency of the dependent-chain versions.
// Pure sums (dinv folded upstream); clamp+zero masks, no serial tail;
// correct global-read fallback for deg > ECAP.
// ---------------------------------------------------------------------------

__global__ __launch_bounds__(256) void agg64_kernel(
    const __half* __restrict__ h, const int* __restrict__ offs,
    const int* __restrict__ offe, const int* __restrict__ esrc,
    const float* __restrict__ dinv, __half* __restrict__ out, int n) {
  __shared__ int eidx[4][ECAP];
  const int wid = threadIdx.x >> 6;
  int gi = blockIdx.x * 4 + wid;
  if (gi >= n) return;
  const int lane = threadIdx.x & 63;
  const int q = lane >> 4;            // edge slot 0..3
  const int j = lane & 15;            // feats 4j..4j+3
  const __half2* hp = (const __half2*)h;
  const float di = dinv[gi];
  const int e0 = offs[gi];
  const int e1 = offe[gi];
  const int deg = e1 - e0;
  const int dm = min(deg, ECAP);
  if (lane < dm) eidx[wid][lane] = esrc[e0 + lane];   // wave-local stage

  float ax = 0.f, ay = 0.f, az = 0.f, aw = 0.f;
  float bx = 0.f, by = 0.f, bz = 0.f, bw = 0.f;
  const int mm = dm - 1;
  for (int k = 0; k < dm; k += 16) {
    int i0 = k + q, i1 = k + 4 + q, i2 = k + 8 + q, i3 = k + 12 + q;
    int s0 = eidx[wid][min(i0, mm)];
    int s1 = eidx[wid][min(i1, mm)];
    int s2 = eidx[wid][min(i2, mm)];
    int s3 = eidx[wid][min(i3, mm)];
    uint2 r0 = *(const uint2*)(hp + (((size_t)s0) << 5) + j * 2);
    uint2 r1 = *(const uint2*)(hp + (((size_t)s1) << 5) + j * 2);
    uint2 r2 = *(const uint2*)(hp + (((size_t)s2) << 5) + j * 2);
    uint2 r3 = *(const uint2*)(hp + (((size_t)s3) << 5) + j * 2);
    if (i0 >= dm) { r0.x = 0u; r0.y = 0u; }
    if (i1 >= dm) { r1.x = 0u; r1.y = 0u; }
    if (i2 >= dm) { r2.x = 0u; r2.y = 0u; }
    if (i3 >= dm) { r3.x = 0u; r3.y = 0u; }
    float2 p0 = __half22float2(*(__half2*)&r0.x);
    float2 p1 = __half22float2(*(__half2*)&r0.y);
    float2 q0 = __half22float2(*(__half2*)&r1.x);
    float2 q1 = __half22float2(*(__half2*)&r1.y);
    float2 u0 = __half22float2(*(__half2*)&r2.x);
    float2 u1 = __half22float2(*(__half2*)&r2.y);
    float2 v0 = __half22float2(*(__half2*)&r3.x);
    float2 v1 = __half22float2(*(__half2*)&r3.y);
    ax += p0.x; ay += p0.y; az += p1.x; aw += p1.y;
    bx += q0.x; by += q0.y; bz += q1.x; bw += q1.y;
    ax += u0.x; ay += u0.y; az += u1.x; aw += u1.y;
    bx += v0.x; by += v0.y; bz += v1.x; bw += v1.y;
  }
  // fallback: deg > ECAP (practically never; kept for correctness)
  for (int e = e0 + ECAP; e < e1; e += 4) {
    int i0 = e + q;
    int s0 = esrc[min(i0, e1 - 1)];
    uint2 r0 = *(const uint2*)(hp + (((size_t)s0) << 5) + j * 2);
    if (i0 >= e1) { r0.x = 0u; r0.y = 0u; }
    float2 p0 = __half22float2(*(__half2*)&r0.x);
    float2 p1 = __half22float2(*(__half2*)&r0.y);
    ax += p0.x; ay += p0.y; az += p1.x; aw += p1.y;
  }
  ax += bx; ay += by; az += bz; aw += bw;
  // combine the 4 edge groups (lanes j, j+16, j+32, j+48 hold same feats)
  ax += __shfl_xor(ax, 16); ay += __shfl_xor(ay, 16);
  az += __shfl_xor(az, 16); aw += __shfl_xor(aw, 16);
  ax += __shfl_xor(ax, 32); ay += __shfl_xor(ay, 32);
  az += __shfl_xor(az, 32); aw += __shfl_xor(aw, 32);
  if (q == 0) {
    uint2 rs = *(const uint2*)(hp + (((size_t)gi) << 5) + j * 2);  // self (scaled)
    float2 s0 = __half22float2(*(__half2*)&rs.x);
    float2 s1 = __half22float2(*(__half2*)&rs.y);
    __half2 h0 = __floats2half2_rn(di * (ax + s0.x), di * (ay + s0.y));
    __half2 h1 = __floats2half2_rn(di * (az + s1.x), di * (aw + s1.y));
    uint2 ov;
    ov.x = *(unsigned*)&h0;
    ov.y = *(unsigned*)&h1;
    *(uint2*)((__half2*)out + (((size_t)gi) << 5) + j * 2) = ov;
  }
}

__global__ __launch_bounds__(256) void agg128_bn_kernel(
    const __half* __restrict__ h, const int* __restrict__ offs,
    const int* __restrict__ offe, const int* __restrict__ esrc,
    const float* __restrict__ dinv,
    const float* __restrict__ bias, const float* __restrict__ gam,
    const float* __restrict__ bet, const float* __restrict__ mean,
    const float* __restrict__ var, __half* __restrict__ out, int n) {
  __shared__ int eidx[4][ECAP];
  const int wid = threadIdx.x >> 6;
  int gi = blockIdx.x * 4 + wid;
  if (gi >= n) return;
  const int lane = threadIdx.x & 63;
  const int hh = lane >> 5;           // half-wave: edge parity
  const int j = lane & 31;            // feats 4j..4j+3
  const __half2* hp = (const __half2*)h;
  const float di = dinv[gi];
  const int e0 = offs[gi];
  const int e1 = offe[gi];
  const int deg = e1 - e0;
  const int dm = min(deg, ECAP);
  if (lane < dm) eidx[wid][lane] = esrc[e0 + lane];   // wave-local stage

  float ax = 0.f, ay = 0.f, az = 0.f, aw = 0.f;
  float bx = 0.f, by = 0.f, bz = 0.f, bw = 0.f;
  const int mm = dm - 1;
  for (int k = 0; k < dm; k += 8) {
    int i0 = k + hh, i1 = k + 2 + hh, i2 = k + 4 + hh, i3 = k + 6 + hh;
    int s0 = eidx[wid][min(i0, mm)];
    int s1 = eidx[wid][min(i1, mm)];
    int s2 = eidx[wid][min(i2, mm)];
    int s3 = eidx[wid][min(i3, mm)];
    uint2 r0 = *(const uint2*)(hp + (((size_t)s0) << 6) + j * 2);
    uint2 r1 = *(const uint2*)(hp + (((size_t)s1) << 6) + j * 2);
    uint2 r2 = *(const uint2*)(hp + (((size_t)s2) << 6) + j * 2);
    uint2 r3 = *(const uint2*)(hp + (((size_t)s3) << 6) + j * 2);
    if (i0 >= dm) { r0.x = 0u; r0.y = 0u; }
    if (i1 >= dm) { r1.x = 0u; r1.y = 0u; }
    if (i2 >= dm) { r2.x = 0u; r2.y = 0u; }
    if (i3 >= dm) { r3.x = 0u; r3.y = 0u; }
    float2 p0 = __half22float2(*(__half2*)&r0.x);
    float2 p1 = __half22float2(*(__half2*)&r0.y);
    float2 q0 = __half22float2(*(__half2*)&r1.x);
    float2 q1 = __half22float2(*(__half2*)&r1.y);
    float2 u0 = __half22float2(*(__half2*)&r2.x);
    float2 u1 = __half22float2(*(__half2*)&r2.y);
    float2 v0 = __half22float2(*(__half2*)&r3.x);
    float2 v1 = __half22float2(*(__half2*)&r3.y);
    ax += p0.x; ay += p0.y; az += p1.x; aw += p1.y;
    bx += q0.x; by += q0.y; bz += q1.x; bw += q1.y;
    ax += u0.x; ay += u0.y; az += u1.x; aw += u1.y;
    bx += v0.x; by += v0.y; bz += v1.x; bw += v1.y;
  }
  // fallback: deg > ECAP (practically never; kept for correctness)
  for (int e = e0 + ECAP; e < e1; e += 2) {
    int i0 = e + hh;
    int s0 = esrc[min(i0, e1 - 1)];
    uint2 r0 = *(const uint2*)(hp + (((size_t)s0) << 6) + j * 2);
    if (i0 >= e1) { r0.x = 0u; r0.y = 0u; }
    float2 p0 = __half22float2(*(__half2*)&r0.x);
    float2 p1 = __half22float2(*(__half2*)&r0.y);
    ax += p0.x; ay += p0.y; az += p1.x; aw += p1.y;
  }
  ax += bx; ay += by; az += bz; aw += bw;
  // combine half-waves (lanes j and j+32 hold same feats, different edges)
  ax += __shfl_xor(ax, 32); ay += __shfl_xor(ay, 32);
  az += __shfl_xor(az, 32); aw += __shfl_xor(aw, 32);
  if (hh == 0) {
    uint2 rs = *(const uint2*)(hp + (((size_t)gi) << 6) + j * 2);  // self (scaled)
    float2 s0 = __half22float2(*(__half2*)&rs.x);
    float2 s1 = __half22float2(*(__half2*)&rs.y);
    float v0 = di * (ax + s0.x);
    float v1 = di * (ay + s0.y);
    float v2 = di * (az + s1.x);
    float v3 = di * (aw + s1.y);
    const int c = j * 4;
    float4 bv = *(const float4*)(bias + c);
    float4 gv = *(const float4*)(gam + c);
    float4 bev = *(const float4*)(bet + c);
    float4 mv = *(const float4*)(mean + c);
    float4 vv = *(const float4*)(var + c);
    float o0 = fmaxf(fmaf(v0 + bv.x - mv.x, gv.x * rsqrtf(vv.x + BN_EPS), bev.x), 0.f);
    float o1 = fmaxf(fmaf(v1 + bv.y - mv.y, gv.y * rsqrtf(vv.y + BN_EPS), bev.y), 0.f);
    float o2 = fmaxf(fmaf(v2 + bv.z - mv.z, gv.z * rsqrtf(vv.z + BN_EPS), bev.z), 0.f);
    float o3 = fmaxf(fmaf(v3 + bv.w - mv.w, gv.w * rsqrtf(vv.w + BN_EPS), bev.w), 0.f);
    __half2 h0 = __floats2half2_rn(o0, o1);
    __half2 h1 = __floats2half2_rn(o2, o3);
    uint2 ov;
    ov.x = *(unsigned*)&h0;
    ov.y = *(unsigned*)&h1;
    *(uint2*)((__half2*)out + (((size_t)gi) << 6) + j * 2) = ov;
  }
}

// ---------------------------------------------------------------------------

static inline size_t alignup(size_t x, size_t a) { return (x + a - 1) & ~(a - 1); }

extern "C" void kernel_launch(void* const* d_in, const int* in_sizes, int n_in,
                              void* d_out, int out_size, void* d_ws, size_t ws_size,
                              hipStream_t stream) {
  const float* x   = (const float*)d_in[0];
  const int*   src = (const int*)d_in[1];
  const int*   dst = (const int*)d_in[2];
  const float* W0  = (const float*)d_in[3];
  const float* b0  = (const float*)d_in[4];
  const float* g0  = (const float*)d_in[5];
  const float* be0 = (const float*)d_in[6];
  const float* m0  = (const float*)d_in[7];
  const float* v0  = (const float*)d_in[8];
  const float* W1  = (const float*)d_in[9];
  const float* b1  = (const float*)d_in[10];
  const float* g1  = (const float*)d_in[11];
  const float* be1 = (const float*)d_in[12];
  const float* m1  = (const float*)d_in[13];
  const float* v1  = (const float*)d_in[14];
  const float* W2  = (const float*)d_in[15];
  const float* b2  = (const float*)d_in[16];
  const float* g2  = (const float*)d_in[17];
  const float* be2 = (const float*)d_in[18];
  const float* m2  = (const float*)d_in[19];
  const float* v2  = (const float*)d_in[20];
  const float* Wm1 = (const float*)d_in[21];
  const float* bm1 = (const float*)d_in[22];
  const float* Wm2 = (const float*)d_in[23];
  const float* bm2 = (const float*)d_in[24];

  const int N = in_sizes[0] / 64;
  const int E = in_sizes[1];

  char* p = (char*)d_ws;
  auto take = [&](size_t bytes) {
    char* r = p;
    p += alignup(bytes, 256);
    return r;
  };
  const int nbk = (N + BK - 1) / BK;    // buckets (98 for N=50000)
  int*    bcursor= (int*)take(NBMAX * 4);
  int*    offs   = (int*)take((size_t)N * 4);
  int*    offe   = (int*)take((size_t)N * 4);
  float*  dinv   = (float*)take((size_t)N * 4);
  int*    esrc   = (int*)take((size_t)nbk * BCAP * 4);
  int2*   tmp    = (int2*)take((size_t)nbk * BCAP * 8);
  __half* x16    = (__half*)take((size_t)N * 64 * 2);
  __half* aggx16 = (__half*)take((size_t)N * 64 * 2);
  __half* t0     = (__half*)take((size_t)N * 128 * 2);
  __half* t1     = (__half*)take((size_t)N * 128 * 2);
  float*  yout   = (float*)d_out;

  const int TB = 256;
  const int sb = (E + ECH - 1) / ECH;   // scatter blocks
  const int n4 = N * 16;                // float4 count of x
  const int cb = (n4 + 255) / 256;      // cvt blocks

  // --- CSR build (fixed-stride buckets) + fp16 x, 3 dispatches total ---
  hipMemsetAsync(bcursor, 0, NBMAX * 4, stream);
  scatter_cvt_kernel<<<sb + cb, TB, 0, stream>>>(src, dst, bcursor, tmp,
                                                 x, x16, E, nbk, sb, n4);
  bucket_finalize_kernel<<<nbk, TB, 0, stream>>>(tmp, bcursor, offs, offe,
                                                 dinv, esrc, x16, N);

  const int gemmGrid = (N + 127) / 128;
  const int aggGrid = (N + 3) / 4;

  // --- layer 0 (x16 rows pre-scaled by dinv in finalize; agg is pure sum) ---
  agg64_kernel<<<aggGrid, TB, 0, stream>>>(x16, offs, offe, esrc, dinv, aggx16, N);
  mgemm_kernel<64, 128, 3, true><<<gemmGrid, TB, 0, stream>>>(
      aggx16, W0, b0, g0, be0, m0, v0, t0, N);
  // --- layer 1 (GEMM pre-scales rows by dinv via EPI=4; agg sums + BN) ---
  mgemm_kernel<128, 128, 4, true><<<gemmGrid, TB, 0, stream>>>(
      t0, W1, dinv, nullptr, nullptr, nullptr, nullptr, t1, N);
  agg128_bn_kernel<<<aggGrid, TB, 0, stream>>>(t1, offs, offe, esrc, dinv,
                                               b1, g1, be1, m1, v1, t0, N);
  // --- layer 2 ---
  mgemm_kernel<128, 128, 4, true><<<gemmGrid, TB, 0, stream>>>(
      t0, W2, dinv, nullptr, nullptr, nullptr, nullptr, t1, N);
  agg128_bn_kernel<<<aggGrid, TB, 0, stream>>>(t1, offs, offe, esrc, dinv,
                                               b2, g2, be2, m2, v2, t0, N);
  // --- fused MLP ---
  mlp_kernel<<<gemmGrid, TB, 0, stream>>>(t0, Wm1, bm1, Wm2, bm2, yout, N);
}

// Round 8
// 311.447 us; speedup vs baseline: 1.9773x; 1.0124x over previous
//
#include <hip/hip_runtime.h>
#include <hip/hip_fp16.h>

#define BN_EPS 1e-5f
#define BK 512        // dst-nodes per bucket (contiguous node range)
#define NBMAX 128
#define ECH 8192      // edges per scatter block
#define BCAP 9216     // fixed per-bucket capacity (mean 8163, sigma~90 -> 11+ sigma)
#define ECAP 64       // staged edge-index capacity per node (Poisson(16): P(>64)~1e-20)

typedef _Float16 half_t;
typedef _Float16 half8 __attribute__((ext_vector_type(8)));
typedef float floatx4 __attribute__((ext_vector_type(4)));

// ---------------------------------------------------------------------------
// Preprocess, fixed-stride buckets: bucket b owns tmp/esrc[b*BCAP ..).
// tmp entries are PACKED: (src<<9)|(dst&511)  (src<2^17, BK=512) -> 4B not 8B.
// ---------------------------------------------------------------------------

// blocks [0, sb): scatter packed {src,dstlocal} into bucket-major tmp.
// blocks [sb, ..): fp32 -> fp16 copy of x (independent work, merged dispatch).
__global__ __launch_bounds__(256) void scatter_cvt_kernel(
    const int* __restrict__ src, const int* __restrict__ dst,
    int* __restrict__ bcursor, unsigned* __restrict__ tmp,
    const float* __restrict__ x, __half* __restrict__ x16,
    int E, int nb, int sb, int n4) {
  const int t = threadIdx.x;
  if (blockIdx.x >= sb) {
    int i = (blockIdx.x - sb) * 256 + t;
    if (i < n4) {
      float4 v = *(const float4*)(x + (size_t)i * 4);
      union { __half h[4]; float2 f; } u;
      u.h[0] = __float2half_rn(v.x);
      u.h[1] = __float2half_rn(v.y);
      u.h[2] = __float2half_rn(v.z);
      u.h[3] = __float2half_rn(v.w);
      *(float2*)(x16 + (size_t)i * 4) = u.f;
    }
    return;
  }
  __shared__ int h[NBMAX];
  for (int i = t; i < nb; i += 256) h[i] = 0;
  __syncthreads();
  const int base = blockIdx.x * ECH;
#pragma unroll 8
  for (int p = 0; p < ECH / 256; ++p) {
    int e = base + p * 256 + t;
    if (e < E) atomicAdd(&h[dst[e] >> 9], 1);
  }
  __syncthreads();
  for (int i = t; i < nb; i += 256) {
    int c = h[i];
    h[i] = c ? (i * BCAP + atomicAdd(&bcursor[i], c)) : 0;  // contiguous run
  }
  __syncthreads();
#pragma unroll 8
  for (int p = 0; p < ECH / 256; ++p) {
    int e = base + p * 256 + t;
    if (e < E) {
      int s = src[e], d = dst[e];
      int pos = atomicAdd(&h[d >> 9], 1);
      tmp[pos] = ((unsigned)s << 9) | (unsigned)(d & 511);
    }
  }
}

// One block per bucket: LDS degree count -> local scan -> offs/offe/dinv/esrc.
// Also pre-scales this bucket's x16 rows by dinv[row] (dinv-fold for layer 0).
__global__ __launch_bounds__(256) void bucket_finalize_kernel(
    const unsigned* __restrict__ tmp, const int* __restrict__ bcursor,
    int* __restrict__ offs, int* __restrict__ offe, float* __restrict__ dinv,
    int* __restrict__ esrc, __half* __restrict__ x16, int n) {
  __shared__ int deg[BK];
  __shared__ int cur[BK];
  __shared__ float fdi[BK];
  __shared__ int ts[256];
  const int t = threadIdx.x;
  const int b = blockIdx.x;
  const int nbase = b * BK;
  const int nn = min(BK, n - nbase);
  const int cnt = bcursor[b];
  const unsigned* tp = tmp + (size_t)b * BCAP;
  for (int i = t; i < nn; i += 256) deg[i] = 0;
  __syncthreads();
  for (int e = t; e < cnt; e += 256)
    atomicAdd(&deg[tp[e] & 511u], 1);
  __syncthreads();
  // exclusive scan of 512 degrees (thread t handles 2t, 2t+1)
  int d0 = (2 * t < nn) ? deg[2 * t] : 0;
  int d1 = (2 * t + 1 < nn) ? deg[2 * t + 1] : 0;
  ts[t] = d0 + d1;
  __syncthreads();
  for (int o = 1; o < 256; o <<= 1) {
    int v = (t >= o) ? ts[t - o] : 0;
    __syncthreads();
    ts[t] += v;
    __syncthreads();
  }
  int base = b * BCAP + ((t == 0) ? 0 : ts[t - 1]);
  if (2 * t < nn) {
    float di = rsqrtf(1.0f + (float)d0);
    offs[nbase + 2 * t] = base;
    offe[nbase + 2 * t] = base + d0;
    cur[2 * t] = base;
    fdi[2 * t] = di;
    dinv[nbase + 2 * t] = di;
  }
  if (2 * t + 1 < nn) {
    float di = rsqrtf(1.0f + (float)d1);
    offs[nbase + 2 * t + 1] = base + d0;
    offe[nbase + 2 * t + 1] = base + d0 + d1;
    cur[2 * t + 1] = base + d0;
    fdi[2 * t + 1] = di;
    dinv[nbase + 2 * t + 1] = di;
  }
  __syncthreads();
  for (int e = t; e < cnt; e += 256) {
    unsigned r = tp[e];
    int pos = atomicAdd(&cur[r & 511u], 1);
    esrc[pos] = (int)(r >> 9);
  }
  // pre-scale x16 rows of this bucket by dinv[row] (32 half2 per row)
  __half2* xp = (__half2*)x16;
  for (int i = t; i < nn * 32; i += 256) {
    int nl = i >> 5;
    size_t idx = (((size_t)(nbase + nl)) << 5) + (i & 31);
    float2 v = __half22float2(xp[idx]);
    float s = fdi[nl];
    xp[idx] = __floats2half2_rn(v.x * s, v.y * s);
  }
}

// ---------------------------------------------------------------------------
// MFMA fp16 GEMM (fp32 accumulate).  256 thr = 4 waves; 128-row tile.
// EPI: 0 none, 1 bias+relu, 2 bias, 3 bias+BN+relu,
//      4 row-scale (bias ptr = per-row dinv; writes dinv[row]*acc).
// ---------------------------------------------------------------------------

template <int FIN, int FOUT, int EPI, bool HALFOUT>
__global__ __launch_bounds__(256) void mgemm_kernel(
    const __half* __restrict__ X, const float* __restrict__ W,
    const float* __restrict__ bias, const float* __restrict__ gam,
    const float* __restrict__ bet, const float* __restrict__ mean,
    const float* __restrict__ var, void* __restrict__ Yv, int n) {
  constexpr int LDK = 72;
  constexpr int NCI = FOUT / 16;
  __shared__ half_t Asm[128 * LDK];
  __shared__ half_t Bsm[FOUT * LDK];

  const int t = threadIdx.x;
  const int wave = t >> 6, lane = t & 63;
  const int quad = lane >> 4, l16 = lane & 15;
  const int rowBase = blockIdx.x * 128;

  floatx4 acc[2][NCI];
#pragma unroll
  for (int i = 0; i < 2; ++i)
#pragma unroll
    for (int ci = 0; ci < NCI; ++ci) acc[i][ci] = (floatx4){0.f, 0.f, 0.f, 0.f};

  for (int kc = 0; kc < FIN; kc += 64) {
    __syncthreads();
    {
      const int kq = t & 15, m0 = t >> 4;
#pragma unroll
      for (int p = 0; p < 8; ++p) {
        int m = p * 16 + m0;
        int row = rowBase + m;
        uint2 v = make_uint2(0u, 0u);
        if (row < n) v = *(const uint2*)(X + (size_t)row * FIN + kc + kq * 4);
        *(uint2*)&Asm[m * LDK + kq * 4] = v;
      }
    }
    {
#pragma unroll
      for (int c0 = 0; c0 < FOUT * 16; c0 += 256) {
        int c = c0 + t;
        int nn = c % FOUT;
        int kg = (c / FOUT) * 4;
        const float* wp = W + (size_t)(kc + kg) * FOUT + nn;
        half_t* d = &Bsm[nn * LDK + kg];
        d[0] = (half_t)wp[0];
        d[1] = (half_t)wp[FOUT];
        d[2] = (half_t)wp[2 * FOUT];
        d[3] = (half_t)wp[3 * FOUT];
      }
    }
    __syncthreads();
#pragma unroll
    for (int kk = 0; kk < 2; ++kk) {
      half8 a0 = *(const half8*)&Asm[(wave * 32 + l16) * LDK + kk * 32 + quad * 8];
      half8 a1 = *(const half8*)&Asm[(wave * 32 + 16 + l16) * LDK + kk * 32 + quad * 8];
#pragma unroll
      for (int ci = 0; ci < NCI; ++ci) {
        half8 b = *(const half8*)&Bsm[(ci * 16 + l16) * LDK + kk * 32 + quad * 8];
        acc[0][ci] = __builtin_amdgcn_mfma_f32_16x16x32_f16(a0, b, acc[0][ci], 0, 0, 0);
        acc[1][ci] = __builtin_amdgcn_mfma_f32_16x16x32_f16(a1, b, acc[1][ci], 0, 0, 0);
      }
    }
  }

  float sc[NCI], sh[NCI];
#pragma unroll
  for (int ci = 0; ci < NCI; ++ci) {
    int col = ci * 16 + l16;
    if constexpr (EPI == 3) {
      float s = gam[col] * rsqrtf(var[col] + BN_EPS);
      sc[ci] = s;
      sh[ci] = (bias[col] - mean[col]) * s + bet[col];
    } else if constexpr (EPI == 1 || EPI == 2) {
      sc[ci] = 1.f;
      sh[ci] = bias[col];
    } else {
      sc[ci] = 1.f;
      sh[ci] = 0.f;
    }
  }
  float rs[2][4];
  if constexpr (EPI == 4) {
#pragma unroll
    for (int ri = 0; ri < 2; ++ri)
#pragma unroll
      for (int r = 0; r < 4; ++r) {
        int row = rowBase + wave * 32 + ri * 16 + quad * 4 + r;
        rs[ri][r] = (row < n) ? bias[row] : 0.f;   // bias ptr = dinv (per-row)
      }
  }
#pragma unroll
  for (int ri = 0; ri < 2; ++ri)
#pragma unroll
    for (int ci = 0; ci < NCI; ++ci) {
      int col = ci * 16 + l16;
#pragma unroll
      for (int r = 0; r < 4; ++r) {
        int row = rowBase + wave * 32 + ri * 16 + quad * 4 + r;
        if (row < n) {
          float v = acc[ri][ci][r];
          if constexpr (EPI == 4) v *= rs[ri][r];
          if constexpr (EPI == 1 || EPI == 2 || EPI == 3) v = fmaf(v, sc[ci], sh[ci]);
          if constexpr (EPI == 1 || EPI == 3) v = fmaxf(v, 0.f);
          if constexpr (HALFOUT)
            ((half_t*)Yv)[(size_t)row * FOUT + col] = (half_t)v;
          else
            ((float*)Yv)[(size_t)row * FOUT + col] = v;
        }
      }
    }
}

// ---------------------------------------------------------------------------
// Fused MLP: Y = relu(X@W1+b1)@W2 + b2.  H kept in LDS (fp16, stride 136).
// ---------------------------------------------------------------------------

__global__ __launch_bounds__(256) void mlp_kernel(
    const __half* __restrict__ X, const float* __restrict__ W1,
    const float* __restrict__ b1f, const float* __restrict__ W2,
    const float* __restrict__ b2f, float* __restrict__ Y, int n) {
  constexpr int LDK = 72;
  constexpr int LDK2 = 136;
  __shared__ half_t smem[(128 + 64) * LDK2];
  half_t* As1 = smem;
  half_t* Bs1 = smem + 128 * LDK;
  half_t* As2 = smem;
  half_t* Bs2 = smem + 128 * LDK2;

  const int t = threadIdx.x;
  const int wave = t >> 6, lane = t & 63;
  const int quad = lane >> 4, l16 = lane & 15;
  const int rowBase = blockIdx.x * 128;

  floatx4 acc[2][8];
#pragma unroll
  for (int i = 0; i < 2; ++i)
#pragma unroll
    for (int ci = 0; ci < 8; ++ci) acc[i][ci] = (floatx4){0.f, 0.f, 0.f, 0.f};

  for (int kc = 0; kc < 128; kc += 64) {
    __syncthreads();
    {
      const int kq = t & 15, m0 = t >> 4;
#pragma unroll
      for (int p = 0; p < 8; ++p) {
        int m = p * 16 + m0;
        int row = rowBase + m;
        uint2 v = make_uint2(0u, 0u);
        if (row < n) v = *(const uint2*)(X + (size_t)row * 128 + kc + kq * 4);
        *(uint2*)&As1[m * LDK + kq * 4] = v;
      }
    }
    {
#pragma unroll
      for (int c0 = 0; c0 < 128 * 16; c0 += 256) {
        int c = c0 + t;
        int nn = c & 127;
        int kg = (c >> 7) << 2;
        const float* wp = W1 + (size_t)(kc + kg) * 128 + nn;
        half_t* d = &Bs1[nn * LDK + kg];
        d[0] = (half_t)wp[0];
        d[1] = (half_t)wp[128];
        d[2] = (half_t)wp[256];
        d[3] = (half_t)wp[384];
      }
    }
    __syncthreads();
#pragma unroll
    for (int kk = 0; kk < 2; ++kk) {
      half8 a0 = *(const half8*)&As1[(wave * 32 + l16) * LDK + kk * 32 + quad * 8];
      half8 a1 = *(const half8*)&As1[(wave * 32 + 16 + l16) * LDK + kk * 32 + quad * 8];
#pragma unroll
      for (int ci = 0; ci < 8; ++ci) {
        half8 b = *(const half8*)&Bs1[(ci * 16 + l16) * LDK + kk * 32 + quad * 8];
        acc[0][ci] = __builtin_amdgcn_mfma_f32_16x16x32_f16(a0, b, acc[0][ci], 0, 0, 0);
        acc[1][ci] = __builtin_amdgcn_mfma_f32_16x16x32_f16(a1, b, acc[1][ci], 0, 0, 0);
      }
    }
  }
  __syncthreads();

#pragma unroll
  for (int ri = 0; ri < 2; ++ri)
#pragma unroll
    for (int ci = 0; ci < 8; ++ci) {
      int col = ci * 16 + l16;
      float bz = b1f[col];
#pragma unroll
      for (int r = 0; r < 4; ++r) {
        int m = wave * 32 + ri * 16 + quad * 4 + r;
        As2[m * LDK2 + col] = (half_t)fmaxf(acc[ri][ci][r] + bz, 0.f);
      }
    }
  {
#pragma unroll
    for (int c0 = 0; c0 < 64 * 32; c0 += 256) {
      int c = c0 + t;
      int nn = c & 63;
      int kg = (c >> 6) << 2;
      const float* wp = W2 + (size_t)kg * 64 + nn;
      half_t* d = &Bs2[nn * LDK2 + kg];
      d[0] = (half_t)wp[0];
      d[1] = (half_t)wp[64];
      d[2] = (half_t)wp[128];
      d[3] = (half_t)wp[192];
    }
  }
  __syncthreads();

  floatx4 acc2[2][4];
#pragma unroll
  for (int i = 0; i < 2; ++i)
#pragma unroll
    for (int ci = 0; ci < 4; ++ci) acc2[i][ci] = (floatx4){0.f, 0.f, 0.f, 0.f};
#pragma unroll
  for (int kk = 0; kk < 4; ++kk) {
    half8 a0 = *(const half8*)&As2[(wave * 32 + l16) * LDK2 + kk * 32 + quad * 8];
    half8 a1 = *(const half8*)&As2[(wave * 32 + 16 + l16) * LDK2 + kk * 32 + quad * 8];
#pragma unroll
    for (int ci = 0; ci < 4; ++ci) {
      half8 b = *(const half8*)&Bs2[(ci * 16 + l16) * LDK2 + kk * 32 + quad * 8];
      acc2[0][ci] = __builtin_amdgcn_mfma_f32_16x16x32_f16(a0, b, acc2[0][ci], 0, 0, 0);
      acc2[1][ci] = __builtin_amdgcn_mfma_f32_16x16x32_f16(a1, b, acc2[1][ci], 0, 0, 0);
    }
  }
#pragma unroll
  for (int ri = 0; ri < 2; ++ri)
#pragma unroll
    for (int ci = 0; ci < 4; ++ci) {
      int col = ci * 16 + l16;
      float bz = b2f[col];
#pragma unroll
      for (int r = 0; r < 4; ++r) {
        int row = rowBase + wave * 32 + ri * 16 + quad * 4 + r;
        if (row < n) Y[(size_t)row * 64 + col] = acc2[ri][ci][r] + bz;
      }
    }
}

// ---------------------------------------------------------------------------
// Aggregations, LDS-staged edge indices, two-tier gather loop:
//   full body:  8 UNMASKED packed row-loads back-to-back (32 lines in
//               flight/wave, zero clamp VALU, zero redundant requests)
//   masked tail: round-7's 4-load clamp+zero body
// Pure sums (dinv folded upstream); global fallback for deg > ECAP.
// ---------------------------------------------------------------------------

__global__ __launch_bounds__(256) void agg64_kernel(
    const __half* __restrict__ h, const int* __restrict__ offs,
    const int* __restrict__ offe, const int* __restrict__ esrc,
    const float* __restrict__ dinv, __half* __restrict__ out, int n) {
  __shared__ int eidx[4][ECAP];
  const int wid = threadIdx.x >> 6;
  int gi = blockIdx.x * 4 + wid;
  if (gi >= n) return;
  const int lane = threadIdx.x & 63;
  const int q = lane >> 4;            // edge slot 0..3
  const int j = lane & 15;            // feats 4j..4j+3
  const __half2* hp = (const __half2*)h;
  const float di = dinv[gi];
  const int e0 = offs[gi];
  const int e1 = offe[gi];
  const int deg = e1 - e0;
  const int dm = min(deg, ECAP);
  if (lane < dm) eidx[wid][lane] = esrc[e0 + lane];   // wave-local stage

  float ax = 0.f, ay = 0.f, az = 0.f, aw = 0.f;
  float bx = 0.f, by = 0.f, bz = 0.f, bw = 0.f;
  int k = 0;
  // full body: 32 edges, 8 unmasked loads
  for (; k + 32 <= dm; k += 32) {
    int s0 = eidx[wid][k + q];
    int s1 = eidx[wid][k + 4 + q];
    int s2 = eidx[wid][k + 8 + q];
    int s3 = eidx[wid][k + 12 + q];
    int s4 = eidx[wid][k + 16 + q];
    int s5 = eidx[wid][k + 20 + q];
    int s6 = eidx[wid][k + 24 + q];
    int s7 = eidx[wid][k + 28 + q];
    uint2 r0 = *(const uint2*)(hp + (((size_t)s0) << 5) + j * 2);
    uint2 r1 = *(const uint2*)(hp + (((size_t)s1) << 5) + j * 2);
    uint2 r2 = *(const uint2*)(hp + (((size_t)s2) << 5) + j * 2);
    uint2 r3 = *(const uint2*)(hp + (((size_t)s3) << 5) + j * 2);
    uint2 r4 = *(const uint2*)(hp + (((size_t)s4) << 5) + j * 2);
    uint2 r5 = *(const uint2*)(hp + (((size_t)s5) << 5) + j * 2);
    uint2 r6 = *(const uint2*)(hp + (((size_t)s6) << 5) + j * 2);
    uint2 r7 = *(const uint2*)(hp + (((size_t)s7) << 5) + j * 2);
    float2 f;
    f = __half22float2(*(__half2*)&r0.x); ax += f.x; ay += f.y;
    f = __half22float2(*(__half2*)&r0.y); az += f.x; aw += f.y;
    f = __half22float2(*(__half2*)&r1.x); bx += f.x; by += f.y;
    f = __half22float2(*(__half2*)&r1.y); bz += f.x; bw += f.y;
    f = __half22float2(*(__half2*)&r2.x); ax += f.x; ay += f.y;
    f = __half22float2(*(__half2*)&r2.y); az += f.x; aw += f.y;
    f = __half22float2(*(__half2*)&r3.x); bx += f.x; by += f.y;
    f = __half22float2(*(__half2*)&r3.y); bz += f.x; bw += f.y;
    f = __half22float2(*(__half2*)&r4.x); ax += f.x; ay += f.y;
    f = __half22float2(*(__half2*)&r4.y); az += f.x; aw += f.y;
    f = __half22float2(*(__half2*)&r5.x); bx += f.x; by += f.y;
    f = __half22float2(*(__half2*)&r5.y); bz += f.x; bw += f.y;
    f = __half22float2(*(__half2*)&r6.x); ax += f.x; ay += f.y;
    f = __half22float2(*(__half2*)&r6.y); az += f.x; aw += f.y;
    f = __half22float2(*(__half2*)&r7.x); bx += f.x; by += f.y;
    f = __half22float2(*(__half2*)&r7.y); bz += f.x; bw += f.y;
  }
  // masked tail: 16 edges, 4 loads, clamp+zero
  const int mm = dm - 1;
  for (; k < dm; k += 16) {
    int i0 = k + q, i1 = k + 4 + q, i2 = k + 8 + q, i3 = k + 12 + q;
    int s0 = eidx[wid][min(i0, mm)];
    int s1 = eidx[wid][min(i1, mm)];
    int s2 = eidx[wid][min(i2, mm)];
    int s3 = eidx[wid][min(i3, mm)];
    uint2 r0 = *(const uint2*)(hp + (((size_t)s0) << 5) + j * 2);
    uint2 r1 = *(const uint2*)(hp + (((size_t)s1) << 5) + j * 2);
    uint2 r2 = *(const uint2*)(hp + (((size_t)s2) << 5) + j * 2);
    uint2 r3 = *(const uint2*)(hp + (((size_t)s3) << 5) + j * 2);
    if (i0 >= dm) { r0.x = 0u; r0.y = 0u; }
    if (i1 >= dm) { r1.x = 0u; r1.y = 0u; }
    if (i2 >= dm) { r2.x = 0u; r2.y = 0u; }
    if (i3 >= dm) { r3.x = 0u; r3.y = 0u; }
    float2 f;
    f = __half22float2(*(__half2*)&r0.x); ax += f.x; ay += f.y;
    f = __half22float2(*(__half2*)&r0.y); az += f.x; aw += f.y;
    f = __half22float2(*(__half2*)&r1.x); bx += f.x; by += f.y;
    f = __half22float2(*(__half2*)&r1.y); bz += f.x; bw += f.y;
    f = __half22float2(*(__half2*)&r2.x); ax += f.x; ay += f.y;
    f = __half22float2(*(__half2*)&r2.y); az += f.x; aw += f.y;
    f = __half22float2(*(__half2*)&r3.x); bx += f.x; by += f.y;
    f = __half22float2(*(__half2*)&r3.y); bz += f.x; bw += f.y;
  }
  // fallback: deg > ECAP (practically never; kept for correctness)
  for (int e = e0 + ECAP; e < e1; e += 4) {
    int i0 = e + q;
    int s0 = esrc[min(i0, e1 - 1)];
    uint2 r0 = *(const uint2*)(hp + (((size_t)s0) << 5) + j * 2);
    if (i0 >= e1) { r0.x = 0u; r0.y = 0u; }
    float2 f;
    f = __half22float2(*(__half2*)&r0.x); ax += f.x; ay += f.y;
    f = __half22float2(*(__half2*)&r0.y); az += f.x; aw += f.y;
  }
  ax += bx; ay += by; az += bz; aw += bw;
  // combine the 4 edge groups (lanes j, j+16, j+32, j+48 hold same feats)
  ax += __shfl_xor(ax, 16); ay += __shfl_xor(ay, 16);
  az += __shfl_xor(az, 16); aw += __shfl_xor(aw, 16);
  ax += __shfl_xor(ax, 32); ay += __shfl_xor(ay, 32);
  az += __shfl_xor(az, 32); aw += __shfl_xor(aw, 32);
  if (q == 0) {
    uint2 rs = *(const uint2*)(hp + (((size_t)gi) << 5) + j * 2);  // self (scaled)
    float2 s0 = __half22float2(*(__half2*)&rs.x);
    float2 s1 = __half22float2(*(__half2*)&rs.y);
    __half2 h0 = __floats2half2_rn(di * (ax + s0.x), di * (ay + s0.y));
    __half2 h1 = __floats2half2_rn(di * (az + s1.x), di * (aw + s1.y));
    uint2 ov;
    ov.x = *(unsigned*)&h0;
    ov.y = *(unsigned*)&h1;
    *(uint2*)((__half2*)out + (((size_t)gi) << 5) + j * 2) = ov;
  }
}

__global__ __launch_bounds__(256) void agg128_bn_kernel(
    const __half* __restrict__ h, const int* __restrict__ offs,
    const int* __restrict__ offe, const int* __restrict__ esrc,
    const float* __restrict__ dinv,
    const float* __restrict__ bias, const float* __restrict__ gam,
    const float* __restrict__ bet, const float* __restrict__ mean,
    const float* __restrict__ var, __half* __restrict__ out, int n) {
  __shared__ int eidx[4][ECAP];
  const int wid = threadIdx.x >> 6;
  int gi = blockIdx.x * 4 + wid;
  if (gi >= n) return;
  const int lane = threadIdx.x & 63;
  const int hh = lane >> 5;           // half-wave: edge parity
  const int j = lane & 31;            // feats 4j..4j+3
  const __half2* hp = (const __half2*)h;
  const float di = dinv[gi];
  const int e0 = offs[gi];
  const int e1 = offe[gi];
  const int deg = e1 - e0;
  const int dm = min(deg, ECAP);
  if (lane < dm) eidx[wid][lane] = esrc[e0 + lane];   // wave-local stage

  float ax = 0.f, ay = 0.f, az = 0.f, aw = 0.f;
  float bx = 0.f, by = 0.f, bz = 0.f, bw = 0.f;
  int k = 0;
  // full body: 16 edges, 8 unmasked loads
  for (; k + 16 <= dm; k += 16) {
    int s0 = eidx[wid][k + hh];
    int s1 = eidx[wid][k + 2 + hh];
    int s2 = eidx[wid][k + 4 + hh];
    int s3 = eidx[wid][k + 6 + hh];
    int s4 = eidx[wid][k + 8 + hh];
    int s5 = eidx[wid][k + 10 + hh];
    int s6 = eidx[wid][k + 12 + hh];
    int s7 = eidx[wid][k + 14 + hh];
    uint2 r0 = *(const uint2*)(hp + (((size_t)s0) << 6) + j * 2);
    uint2 r1 = *(const uint2*)(hp + (((size_t)s1) << 6) + j * 2);
    uint2 r2 = *(const uint2*)(hp + (((size_t)s2) << 6) + j * 2);
    uint2 r3 = *(const uint2*)(hp + (((size_t)s3) << 6) + j * 2);
    uint2 r4 = *(const uint2*)(hp + (((size_t)s4) << 6) + j * 2);
    uint2 r5 = *(const uint2*)(hp + (((size_t)s5) << 6) + j * 2);
    uint2 r6 = *(const uint2*)(hp + (((size_t)s6) << 6) + j * 2);
    uint2 r7 = *(const uint2*)(hp + (((size_t)s7) << 6) + j * 2);
    float2 f;
    f = __half22float2(*(__half2*)&r0.x); ax += f.x; ay += f.y;
    f = __half22float2(*(__half2*)&r0.y); az += f.x; aw += f.y;
    f = __half22float2(*(__half2*)&r1.x); bx += f.x; by += f.y;
    f = __half22float2(*(__half2*)&r1.y); bz += f.x; bw += f.y;
    f = __half22float2(*(__half2*)&r2.x); ax += f.x; ay += f.y;
    f = __half22float2(*(__half2*)&r2.y); az += f.x; aw += f.y;
    f = __half22float2(*(__half2*)&r3.x); bx += f.x; by += f.y;
    f = __half22float2(*(__half2*)&r3.y); bz += f.x; bw += f.y;
    f = __half22float2(*(__half2*)&r4.x); ax += f.x; ay += f.y;
    f = __half22float2(*(__half2*)&r4.y); az += f.x; aw += f.y;
    f = __half22float2(*(__half2*)&r5.x); bx += f.x; by += f.y;
    f = __half22float2(*(__half2*)&r5.y); bz += f.x; bw += f.y;
    f = __half22float2(*(__half2*)&r6.x); ax += f.x; ay += f.y;
    f = __half22float2(*(__half2*)&r6.y); az += f.x; aw += f.y;
    f = __half22float2(*(__half2*)&r7.x); bx += f.x; by += f.y;
    f = __half22float2(*(__half2*)&r7.y); bz += f.x; bw += f.y;
  }
  // masked tail: 8 edges, 4 loads, clamp+zero
  const int mm = dm - 1;
  for (; k < dm; k += 8) {
    int i0 = k + hh, i1 = k + 2 + hh, i2 = k + 4 + hh, i3 = k + 6 + hh;
    int s0 = eidx[wid][min(i0, mm)];
    int s1 = eidx[wid][min(i1, mm)];
    int s2 = eidx[wid][min(i2, mm)];
    int s3 = eidx[wid][min(i3, mm)];
    uint2 r0 = *(const uint2*)(hp + (((size_t)s0) << 6) + j * 2);
    uint2 r1 = *(const uint2*)(hp + (((size_t)s1) << 6) + j * 2);
    uint2 r2 = *(const uint2*)(hp + (((size_t)s2) << 6) + j * 2);
    uint2 r3 = *(const uint2*)(hp + (((size_t)s3) << 6) + j * 2);
    if (i0 >= dm) { r0.x = 0u; r0.y = 0u; }
    if (i1 >= dm) { r1.x = 0u; r1.y = 0u; }
    if (i2 >= dm) { r2.x = 0u; r2.y = 0u; }
    if (i3 >= dm) { r3.x = 0u; r3.y = 0u; }
    float2 f;
    f = __half22float2(*(__half2*)&r0.x); ax += f.x; ay += f.y;
    f = __half22float2(*(__half2*)&r0.y); az += f.x; aw += f.y;
    f = __half22float2(*(__half2*)&r1.x); bx += f.x; by += f.y;
    f = __half22float2(*(__half2*)&r1.y); bz += f.x; bw += f.y;
    f = __half22float2(*(__half2*)&r2.x); ax += f.x; ay += f.y;
    f = __half22float2(*(__half2*)&r2.y); az += f.x; aw += f.y;
    f = __half22float2(*(__half2*)&r3.x); bx += f.x; by += f.y;
    f = __half22float2(*(__half2*)&r3.y); bz += f.x; bw += f.y;
  }
  // fallback: deg > ECAP (practically never; kept for correctness)
  for (int e = e0 + ECAP; e < e1; e += 2) {
    int i0 = e + hh;
    int s0 = esrc[min(i0, e1 - 1)];
    uint2 r0 = *(const uint2*)(hp + (((size_t)s0) << 6) + j * 2);
    if (i0 >= e1) { r0.x = 0u; r0.y = 0u; }
    float2 f;
    f = __half22float2(*(__half2*)&r0.x); ax += f.x; ay += f.y;
    f = __half22float2(*(__half2*)&r0.y); az += f.x; aw += f.y;
  }
  ax += bx; ay += by; az += bz; aw += bw;
  // combine half-waves (lanes j and j+32 hold same feats, different edges)
  ax += __shfl_xor(ax, 32); ay += __shfl_xor(ay, 32);
  az += __shfl_xor(az, 32); aw += __shfl_xor(aw, 32);
  if (hh == 0) {
    uint2 rs = *(const uint2*)(hp + (((size_t)gi) << 6) + j * 2);  // self (scaled)
    float2 s0 = __half22float2(*(__half2*)&rs.x);
    float2 s1 = __half22float2(*(__half2*)&rs.y);
    float v0 = di * (ax + s0.x);
    float v1 = di * (ay + s0.y);
    float v2 = di * (az + s1.x);
    float v3 = di * (aw + s1.y);
    const int c = j * 4;
    float4 bv = *(const float4*)(bias + c);
    float4 gv = *(const float4*)(gam + c);
    float4 bev = *(const float4*)(bet + c);
    float4 mv = *(const float4*)(mean + c);
    float4 vv = *(const float4*)(var + c);
    float o0 = fmaxf(fmaf(v0 + bv.x - mv.x, gv.x * rsqrtf(vv.x + BN_EPS), bev.x), 0.f);
    float o1 = fmaxf(fmaf(v1 + bv.y - mv.y, gv.y * rsqrtf(vv.y + BN_EPS), bev.y), 0.f);
    float o2 = fmaxf(fmaf(v2 + bv.z - mv.z, gv.z * rsqrtf(vv.z + BN_EPS), bev.z), 0.f);
    float o3 = fmaxf(fmaf(v3 + bv.w - mv.w, gv.w * rsqrtf(vv.w + BN_EPS), bev.w), 0.f);
    __half2 h0 = __floats2half2_rn(o0, o1);
    __half2 h1 = __floats2half2_rn(o2, o3);
    uint2 ov;
    ov.x = *(unsigned*)&h0;
    ov.y = *(unsigned*)&h1;
    *(uint2*)((__half2*)out + (((size_t)gi) << 6) + j * 2) = ov;
  }
}

// ---------------------------------------------------------------------------

static inline size_t alignup(size_t x, size_t a) { return (x + a - 1) & ~(a - 1); }

extern "C" void kernel_launch(void* const* d_in, const int* in_sizes, int n_in,
                              void* d_out, int out_size, void* d_ws, size_t ws_size,
                              hipStream_t stream) {
  const float* x   = (const float*)d_in[0];
  const int*   src = (const int*)d_in[1];
  const int*   dst = (const int*)d_in[2];
  const float* W0  = (const float*)d_in[3];
  const float* b0  = (const float*)d_in[4];
  const float* g0  = (const float*)d_in[5];
  const float* be0 = (const float*)d_in[6];
  const float* m0  = (const float*)d_in[7];
  const float* v0  = (const float*)d_in[8];
  const float* W1  = (const float*)d_in[9];
  const float* b1  = (const float*)d_in[10];
  const float* g1  = (const float*)d_in[11];
  const float* be1 = (const float*)d_in[12];
  const float* m1  = (const float*)d_in[13];
  const float* v1  = (const float*)d_in[14];
  const float* W2  = (const float*)d_in[15];
  const float* b2  = (const float*)d_in[16];
  const float* g2  = (const float*)d_in[17];
  const float* be2 = (const float*)d_in[18];
  const float* m2  = (const float*)d_in[19];
  const float* v2  = (const float*)d_in[20];
  const float* Wm1 = (const float*)d_in[21];
  const float* bm1 = (const float*)d_in[22];
  const float* Wm2 = (const float*)d_in[23];
  const float* bm2 = (const float*)d_in[24];

  const int N = in_sizes[0] / 64;
  const int E = in_sizes[1];

  char* p = (char*)d_ws;
  auto take = [&](size_t bytes) {
    char* r = p;
    p += alignup(bytes, 256);
    return r;
  };
  const int nbk = (N + BK - 1) / BK;    // buckets (98 for N=50000)
  int*      bcursor= (int*)take(NBMAX * 4);
  int*      offs   = (int*)take((size_t)N * 4);
  int*      offe   = (int*)take((size_t)N * 4);
  float*    dinv   = (float*)take((size_t)N * 4);
  int*      esrc   = (int*)take((size_t)nbk * BCAP * 4);
  unsigned* tmp    = (unsigned*)take((size_t)nbk * BCAP * 4);
  __half*   x16    = (__half*)take((size_t)N * 64 * 2);
  __half*   aggx16 = (__half*)take((size_t)N * 64 * 2);
  __half*   t0     = (__half*)take((size_t)N * 128 * 2);
  __half*   t1     = (__half*)take((size_t)N * 128 * 2);
  float*    yout   = (float*)d_out;

  const int TB = 256;
  const int sb = (E + ECH - 1) / ECH;   // scatter blocks
  const int n4 = N * 16;                // float4 count of x
  const int cb = (n4 + 255) / 256;      // cvt blocks

  // --- CSR build (fixed-stride buckets) + fp16 x, 3 dispatches total ---
  hipMemsetAsync(bcursor, 0, NBMAX * 4, stream);
  scatter_cvt_kernel<<<sb + cb, TB, 0, stream>>>(src, dst, bcursor, tmp,
                                                 x, x16, E, nbk, sb, n4);
  bucket_finalize_kernel<<<nbk, TB, 0, stream>>>(tmp, bcursor, offs, offe,
                                                 dinv, esrc, x16, N);

  const int gemmGrid = (N + 127) / 128;
  const int aggGrid = (N + 3) / 4;

  // --- layer 0 (x16 rows pre-scaled by dinv in finalize; agg is pure sum) ---
  agg64_kernel<<<aggGrid, TB, 0, stream>>>(x16, offs, offe, esrc, dinv, aggx16, N);
  mgemm_kernel<64, 128, 3, true><<<gemmGrid, TB, 0, stream>>>(
      aggx16, W0, b0, g0, be0, m0, v0, t0, N);
  // --- layer 1 (GEMM pre-scales rows by dinv via EPI=4; agg sums + BN) ---
  mgemm_kernel<128, 128, 4, true><<<gemmGrid, TB, 0, stream>>>(
      t0, W1, dinv, nullptr, nullptr, nullptr, nullptr, t1, N);
  agg128_bn_kernel<<<aggGrid, TB, 0, stream>>>(t1, offs, offe, esrc, dinv,
                                               b1, g1, be1, m1, v1, t0, N);
  // --- layer 2 ---
  mgemm_kernel<128, 128, 4, true><<<gemmGrid, TB, 0, stream>>>(
      t0, W2, dinv, nullptr, nullptr, nullptr, nullptr, t1, N);
  agg128_bn_kernel<<<aggGrid, TB, 0, stream>>>(t1, offs, offe, esrc, dinv,
                                               b2, g2, be2, m2, v2, t0, N);
  // --- fused MLP ---
  mlp_kernel<<<gemmGrid, TB, 0, stream>>>(t0, Wm1, bm1, Wm2, bm2, yout, N);
}